// Round 14
// baseline (414.024 us; speedup 1.0000x reference)
//
#include <hip/hip_runtime.h>
#include <hip/hip_bf16.h>

// ---------------- problem constants ----------------
#define NU 40000
#define EU 640000
#define BB 64
#define TT 16
#define NW 30
#define NTNODES 30720       // B*T*NW
#define NTE 61440           // tweet edges
#define NSEG_T 1024         // B*T
#define NCHUNK 16           // chunks per user segment for att-pool
#define NBU 157             // ceil(NU/256)
#define NBT 120             // NTNODES/256

typedef __attribute__((ext_vector_type(8))) short bf16x8;
typedef __attribute__((ext_vector_type(4))) float f32x4;

__device__ __forceinline__ unsigned short f2bf(float x) {
    union { float f; unsigned u; } v; v.f = x;
    unsigned r = v.u + 0x7FFFu + ((v.u >> 16) & 1u);   // RNE
    return (unsigned short)(r >> 16);
}
__device__ __forceinline__ float bf2f(unsigned short u) {
    union { unsigned u; float f; } v; v.u = (unsigned)u << 16; return v.f;
}
// async 16B global->LDS (per-lane global src; LDS dest = wave-uniform base + lane*16)
__device__ __forceinline__ void gld16(const unsigned short* g, unsigned short* l) {
    __builtin_amdgcn_global_load_lds(
        (const __attribute__((address_space(1))) void*)g,
        (__attribute__((address_space(3))) void*)l, 16, 0, 0);
}

// ---------------- degree / CSR build (fused user+tweet) ----------------
__global__ void k_zeroint(int* __restrict__ p, int n) {
    int i = blockIdx.x * blockDim.x + threadIdx.x;
    if (i < n) p[i] = 0;
}

__global__ void k_hist2(const int* __restrict__ ue_dst, const int* __restrict__ te_dst,
                        int* __restrict__ hist_u, int* __restrict__ hist_t) {
    int i = blockIdx.x * blockDim.x + threadIdx.x;
    if (i < EU) atomicAdd(&hist_u[ue_dst[i]], 1);
    else if (i < EU + NTE) atomicAdd(&hist_t[te_dst[i - EU]], 1);
}

__global__ __launch_bounds__(256) void k_scan_a2(const int* __restrict__ hist_u,
                                                 int* __restrict__ bsum_u,
                                                 int* __restrict__ bsum_t) {
    __shared__ int red[256];
    int b = blockIdx.x, t = threadIdx.x;
    const int* h; int* bs; int n, lb;
    if (b < NBU) { h = hist_u;      bs = bsum_u; n = NU;      lb = b; }
    else         { h = hist_u + NU; bs = bsum_t; n = NTNODES; lb = b - NBU; }
    int i = lb * 256 + t;
    red[t] = (i < n) ? h[i] : 0;
    __syncthreads();
    for (int off = 128; off; off >>= 1) {
        if (t < off) red[t] += red[t + off];
        __syncthreads();
    }
    if (t == 0) bs[lb] = red[0];
}

__global__ __launch_bounds__(256) void k_scan_b2(int* __restrict__ bsum_u,
                                                 int* __restrict__ bsum_t) {
    __shared__ int s[256];
    int t = threadIdx.x;
    int* bs = blockIdx.x ? bsum_t : bsum_u;
    int nb  = blockIdx.x ? NBT : NBU;
    s[t] = (t < nb) ? bs[t] : 0;
    __syncthreads();
    for (int off = 1; off < 256; off <<= 1) {
        int v = (t >= off) ? s[t - off] : 0;
        __syncthreads();
        s[t] += v;
        __syncthreads();
    }
    if (t < nb) bs[t] = (t == 0) ? 0 : s[t - 1];
}

__global__ __launch_bounds__(256) void k_scan_c2(const int* __restrict__ hist_u,
                                                 const int* __restrict__ bsum_u,
                                                 const int* __restrict__ bsum_t,
                                                 int* __restrict__ ptr_u, int* __restrict__ fill_u,
                                                 int* __restrict__ ptr_t, int* __restrict__ fill_t,
                                                 float* __restrict__ dinv_u) {
    __shared__ int s[256];
    int b = blockIdx.x, t = threadIdx.x;
    const int *h, *bs; int *ptr, *fill; int n, lb; float* dv;
    if (b < NBU) { h = hist_u;      bs = bsum_u; ptr = ptr_u; fill = fill_u; n = NU;      lb = b;       dv = dinv_u; }
    else         { h = hist_u + NU; bs = bsum_t; ptr = ptr_t; fill = fill_t; n = NTNODES; lb = b - NBU; dv = dinv_u + NU; }
    int i = lb * 256 + t;
    int hv = (i < n) ? h[i] : 0;
    s[t] = hv;
    __syncthreads();
    for (int off = 1; off < 256; off <<= 1) {
        int v = (t >= off) ? s[t - off] : 0;
        __syncthreads();
        s[t] += v;
        __syncthreads();
    }
    if (i < n) {
        int excl = bs[lb] + s[t] - hv;
        ptr[i] = excl;
        fill[i] = excl;
        dv[i] = rsqrtf((float)hv + 1.0f);
        if (i == n - 1) ptr[n] = excl + hv;
    }
}

__global__ void k_place2(const int* __restrict__ ue_src, const int* __restrict__ ue_dst,
                         const int* __restrict__ te_src, const int* __restrict__ te_dst,
                         int* __restrict__ fill_u, int* __restrict__ esrc_u,
                         int* __restrict__ fill_t, int* __restrict__ esrc_t) {
    int e = blockIdx.x * blockDim.x + threadIdx.x;
    if (e < EU) {
        int pos = atomicAdd(&fill_u[ue_dst[e]], 1);
        esrc_u[pos] = ue_src[e];
    } else if (e < EU + NTE) {
        int e2 = e - EU;
        int pos = atomicAdd(&fill_t[te_dst[e2]], 1);
        esrc_t[pos] = te_src[e2];
    }
}

// ---------------- weight pre-pack (9 weights + W_hh transpose, one kernel) ------------
__device__ __forceinline__ void pack_one(const float* __restrict__ W,
                                         unsigned short* __restrict__ out,
                                         int f, int K, int N, int trans) {
    int j = f & 7;
    int chunk = f >> 3;
    int c = chunk & 511;
    int panel = chunk >> 9;
    int KS = K >> 5;
    int ks = panel % KS;
    int bn = panel / KS;
    int n = bn * 128 + (c & 127);
    int k = ks * 32 + (c >> 7) * 8 + j;
    float v = trans ? W[(size_t)n * K + k] : W[(size_t)k * N + n];
    out[f] = f2bf(v);
}

__global__ void k_packall(const float* __restrict__ Wu0, const float* __restrict__ Wu1,
                          const float* __restrict__ Wgu1, const float* __restrict__ Wgu2,
                          const float* __restrict__ Wt0, const float* __restrict__ Wt1,
                          const float* __restrict__ Wgt1, const float* __restrict__ Wgt2,
                          const float* __restrict__ Wih,
                          const float* __restrict__ Whh, float* __restrict__ whhT,
                          unsigned short* __restrict__ pk) {
    int f = blockIdx.x * blockDim.x + threadIdx.x;
    if (f < 16384)        pack_one(Wu0,  pk + 0,      f,          128, 128, 0);
    else if (f < 32768)   pack_one(Wu1,  pk + 16384,  f - 16384,  128, 128, 0);
    else if (f < 49152)   pack_one(Wgu1, pk + 32768,  f - 32768,  128, 128, 0);
    else if (f < 65536)   pack_one(Wgu2, pk + 49152,  f - 49152,  128, 128, 0);
    else if (f < 262144)  pack_one(Wt0,  pk + 65536,  f - 65536,  768, 256, 0);
    else if (f < 294912)  pack_one(Wt1,  pk + 262144, f - 262144, 256, 128, 0);
    else if (f < 311296)  pack_one(Wgt1, pk + 294912, f - 294912, 128, 128, 0);
    else if (f < 327680)  pack_one(Wgt2, pk + 311296, f - 311296, 128, 128, 0);
    else if (f < 376832)  pack_one(Wih,  pk + 327680, f - 327680, 128, 384, 1);
    else if (f < 425984) {                          // W_hh [384][128] -> whhT [128][384]
        int j2 = f - 376832;
        int r = j2 >> 7, k2 = j2 & 127;
        whhT[k2 * 384 + r] = Whh[j2];
    }
}

// ---------------- bf16 MFMA GEMM body, BM=32 BN=128 BK=32, 2-phase double-buffer ------
// AF32: A fp32 (T14 split: global->reg issue before MFMA, convert+ds_write after).
// !AF32: A bf16 via global_load_lds (fire-and-forget).
// One __syncthreads per K-step; next tile's loads issued before current compute.
// flags: 1=bias, 2=relu, 4=fp32 out. dscale: row scale (pre-bias). M%32, K%32, N%128.
template<bool AF32>
__device__ __forceinline__ void mgemm_body(const void* __restrict__ Araw,
                                           const unsigned short* __restrict__ Bpk,
                                           const float* __restrict__ bias,
                                           const float* __restrict__ dscale,
                                           void* __restrict__ Craw,
                                           int M, int K, int N, int flags,
                                           int bm, int bn,
                                           unsigned short* Alds, unsigned short* Blds) {
    constexpr int AST = AF32 ? 260 : 256;     // hw per kblk plane (pad for fp32 write path)
    constexpr int ABUF = 4 * AST;             // hw per A buffer
    int tid = threadIdx.x, lane = tid & 63, w = tid >> 6;
    int wr = (w >> 1) * 16, wc = (w & 1) * 64;
    int l15 = lane & 15, lk = lane >> 4;

    f32x4 acc[4];
#pragma unroll
    for (int n = 0; n < 4; ++n) acc[n] = (f32x4){0.f, 0.f, 0.f, 0.f};

    int KS = K >> 5;
    const unsigned short* Bpanel = Bpk + (size_t)bn * KS * 4096;
    const float* Af = (const float*)Araw;
    const unsigned short* Ab = (const unsigned short*)Araw;
    int arow32 = tid >> 3, akq = tid & 7;     // AF32 staging coords (1 float4/thread)

    // ---- prologue: stage tile 0 into buf 0 ----
    {
        const unsigned short* bg = Bpanel;
#pragma unroll
        for (int q = 0; q < 2; ++q) {
            int i = w * 2 + q;
            gld16(bg + i * 512 + lane * 8, &Blds[i * 512]);
        }
        if (AF32) {
            float4 av = *(const float4*)(Af + (size_t)(bm * 32 + arow32) * K + akq * 4);
            unsigned lo = (unsigned)f2bf(av.x) | ((unsigned)f2bf(av.y) << 16);
            unsigned hi = (unsigned)f2bf(av.z) | ((unsigned)f2bf(av.w) << 16);
            *(uint2*)&Alds[(akq >> 1) * AST + arow32 * 8 + (akq & 1) * 4] = make_uint2(lo, hi);
        } else if (w < 2) {
            gld16(Ab + (size_t)(bm * 32 + (lane & 31)) * K + (2 * w + (lane >> 5)) * 8,
                  &Alds[w * 512]);
        }
    }
    __syncthreads();

    for (int ks = 0; ks < KS; ++ks) {
        int cur = ks & 1, nxt = cur ^ 1;
        bool have = (ks + 1 < KS);
        float4 av;
        // ---- issue next tile's loads (before compute) ----
        if (have) {
            const unsigned short* bg = Bpanel + (size_t)(ks + 1) * 4096;
            unsigned short* Bn = Blds + nxt * 4096;
#pragma unroll
            for (int q = 0; q < 2; ++q) {
                int i = w * 2 + q;
                gld16(bg + i * 512 + lane * 8, &Bn[i * 512]);
            }
            if (AF32) {
                av = *(const float4*)(Af + (size_t)(bm * 32 + arow32) * K + (ks + 1) * 32 + akq * 4);
            } else if (w < 2) {
                gld16(Ab + (size_t)(bm * 32 + (lane & 31)) * K + (ks + 1) * 32 + (2 * w + (lane >> 5)) * 8,
                      &Alds[nxt * ABUF + w * 512]);
            }
        }
        // ---- compute current tile ----
        {
            const unsigned short* Ac = Alds + cur * ABUF;
            const unsigned short* Bc = Blds + cur * 4096;
            bf16x8 a = *(const bf16x8*)&Ac[lk * AST + (wr + l15) * 8];
            bf16x8 b[4];
#pragma unroll
            for (int n = 0; n < 4; ++n)
                b[n] = *(const bf16x8*)&Bc[lk * 1024 + (wc + n * 16 + l15) * 8];
#pragma unroll
            for (int n = 0; n < 4; ++n)
                acc[n] = __builtin_amdgcn_mfma_f32_16x16x32_bf16(a, b[n], acc[n], 0, 0, 0);
        }
        // ---- AF32: convert + LDS-write next A (after MFMAs; T14 write-late) ----
        if (AF32 && have) {
            unsigned lo = (unsigned)f2bf(av.x) | ((unsigned)f2bf(av.y) << 16);
            unsigned hi = (unsigned)f2bf(av.z) | ((unsigned)f2bf(av.w) << 16);
            *(uint2*)&Alds[nxt * ABUF + (akq >> 1) * AST + arow32 * 8 + (akq & 1) * 4] =
                make_uint2(lo, hi);
        }
        __syncthreads();
    }

    int grow0 = bm * 32 + wr + lk * 4;
#pragma unroll
    for (int i = 0; i < 4; ++i) {
        int grow = grow0 + i;
        float ds = dscale ? dscale[grow] : 1.f;
#pragma unroll
        for (int n = 0; n < 4; ++n) {
            int gcol = bn * 128 + wc + n * 16 + l15;
            float v = acc[n][i] * ds;
            if (flags & 1) v += bias[gcol];
            if (flags & 2) v = fmaxf(v, 0.f);
            if (flags & 4) ((float*)Craw)[(size_t)grow * N + gcol] = v;
            else ((unsigned short*)Craw)[(size_t)grow * N + gcol] = f2bf(v);
        }
    }
}

template<bool AF32>
__global__ __launch_bounds__(256) void k_mgemm(const void* __restrict__ Araw,
                                               const unsigned short* __restrict__ Bpk,
                                               const float* __restrict__ bias,
                                               const float* __restrict__ dscale,
                                               void* __restrict__ Craw,
                                               int M, int K, int N, int flags) {
    constexpr int AST = AF32 ? 260 : 256;
    __shared__ unsigned short Alds[2 * 4 * AST];
    __shared__ unsigned short Blds[2 * 4096];
    if (blockIdx.x * 32 >= M) return;
    mgemm_body<AF32>(Araw, Bpk, bias, dscale, Craw, M, K, N, flags,
                     blockIdx.x, blockIdx.y, Alds, Blds);
}

// dual GEMM: grid.y in [0,bnSplit) -> set 0, [bnSplit,..) -> set 1
template<bool AF32>
__global__ __launch_bounds__(256) void k_mgemm_dual(
        const void* __restrict__ A0, const unsigned short* __restrict__ B0,
        const float* __restrict__ ds0, void* __restrict__ C0, int M0, int K0, int N0,
        const void* __restrict__ A1, const unsigned short* __restrict__ B1,
        const float* __restrict__ ds1, void* __restrict__ C1, int M1, int K1, int N1,
        int bnSplit) {
    constexpr int AST = AF32 ? 260 : 256;
    __shared__ unsigned short Alds[2 * 4 * AST];
    __shared__ unsigned short Blds[2 * 4096];
    int bn = blockIdx.y, bm = blockIdx.x;
    if (bn < bnSplit) {
        if (bm * 32 >= M0) return;
        mgemm_body<AF32>(A0, B0, (const float*)nullptr, ds0, C0, M0, K0, N0, 0,
                         bm, bn, Alds, Blds);
    } else {
        if (bm * 32 >= M1) return;
        mgemm_body<AF32>(A1, B1, (const float*)nullptr, ds1, C1, M1, K1, N1, 0,
                         bm, bn - bnSplit, Alds, Blds);
    }
}

// ---------------- fused gate pair body: out = (X@W1+b1)@W2+b2, K=N=128 ---------------
__device__ __forceinline__ void gatepair_body(const unsigned short* __restrict__ X,
                                              const unsigned short* __restrict__ W1,
                                              const float* __restrict__ b1,
                                              const unsigned short* __restrict__ W2,
                                              const float* __restrict__ b2,
                                              unsigned short* __restrict__ outp,
                                              int bm,
                                              unsigned short* Ax, unsigned short* Wl) {
    int tid = threadIdx.x, lane = tid & 63, w = tid >> 6;
    int wr = (w >> 1) * 32, wc = (w & 1) * 64;
    int l15 = lane & 15, lk = lane >> 4;

#pragma unroll
    for (int q = 0; q < 4; ++q) {
        int pl = w * 4 + q;
        gld16(X + (size_t)(bm * 64 + lane) * 128 + pl * 8, &Ax[pl * 512]);
    }

    f32x4 acc[2][4];
#pragma unroll
    for (int m = 0; m < 2; ++m)
#pragma unroll
        for (int n = 0; n < 4; ++n) acc[m][n] = (f32x4){0.f, 0.f, 0.f, 0.f};

    for (int ks = 0; ks < 2; ++ks) {
        const unsigned short* wp = W1 + ks * 8192;
#pragma unroll
        for (int q = 0; q < 4; ++q) {
            int off = (w * 4 + q) * 512;
            gld16(wp + off + lane * 8, &Wl[off]);
        }
        __syncthreads();
#pragma unroll
        for (int h = 0; h < 2; ++h) {
            int kb = h * 4 + lk;
            bf16x8 a[2], b[4];
#pragma unroll
            for (int m = 0; m < 2; ++m)
                a[m] = *(const bf16x8*)&Ax[(ks * 8 + kb) * 512 + (wr + m * 16 + l15) * 8];
#pragma unroll
            for (int n = 0; n < 4; ++n)
                b[n] = *(const bf16x8*)&Wl[kb * 1024 + (wc + n * 16 + l15) * 8];
#pragma unroll
            for (int m = 0; m < 2; ++m)
#pragma unroll
                for (int n = 0; n < 4; ++n)
                    acc[m][n] = __builtin_amdgcn_mfma_f32_16x16x32_bf16(a[m], b[n], acc[m][n], 0, 0, 0);
        }
        __syncthreads();
    }

#pragma unroll
    for (int m = 0; m < 2; ++m)
#pragma unroll
        for (int n = 0; n < 4; ++n) {
            int col = wc + n * 16 + l15;
            float bv = b1[col];
#pragma unroll
            for (int i = 0; i < 4; ++i) {
                int row = wr + m * 16 + lk * 4 + i;
                float v = acc[m][n][i] + bv;     // NO relu (Linear->Linear)
                Ax[(col >> 3) * 512 + row * 8 + (col & 7)] = f2bf(v);
            }
        }
    __syncthreads();

#pragma unroll
    for (int m = 0; m < 2; ++m)
#pragma unroll
        for (int n = 0; n < 4; ++n) acc[m][n] = (f32x4){0.f, 0.f, 0.f, 0.f};
    for (int ks = 0; ks < 2; ++ks) {
        const unsigned short* wp = W2 + ks * 8192;
#pragma unroll
        for (int q = 0; q < 4; ++q) {
            int off = (w * 4 + q) * 512;
            gld16(wp + off + lane * 8, &Wl[off]);
        }
        __syncthreads();
#pragma unroll
        for (int h = 0; h < 2; ++h) {
            int kb = h * 4 + lk;
            bf16x8 a[2], b[4];
#pragma unroll
            for (int m = 0; m < 2; ++m)
                a[m] = *(const bf16x8*)&Ax[(ks * 8 + kb) * 512 + (wr + m * 16 + l15) * 8];
#pragma unroll
            for (int n = 0; n < 4; ++n)
                b[n] = *(const bf16x8*)&Wl[kb * 1024 + (wc + n * 16 + l15) * 8];
#pragma unroll
            for (int m = 0; m < 2; ++m)
#pragma unroll
                for (int n = 0; n < 4; ++n)
                    acc[m][n] = __builtin_amdgcn_mfma_f32_16x16x32_bf16(a[m], b[n], acc[m][n], 0, 0, 0);
        }
        __syncthreads();
    }

#pragma unroll
    for (int m = 0; m < 2; ++m)
#pragma unroll
        for (int n = 0; n < 4; ++n) {
            int col = wc + n * 16 + l15;
            float bv = b2[col];
#pragma unroll
            for (int i = 0; i < 4; ++i) {
                int row = bm * 64 + wr + m * 16 + lk * 4 + i;
                float v = acc[m][n][i] + bv;     // NO relu
                outp[(size_t)row * 128 + col] = f2bf(v);
            }
        }
}

__global__ __launch_bounds__(256) void k_gatepair2(
        const unsigned short* __restrict__ X0, const unsigned short* __restrict__ W10,
        const float* __restrict__ b10, const unsigned short* __restrict__ W20,
        const float* __restrict__ b20, unsigned short* __restrict__ O0, int nb0,
        const unsigned short* __restrict__ X1, const unsigned short* __restrict__ W11,
        const float* __restrict__ b11, const unsigned short* __restrict__ W21,
        const float* __restrict__ b21, unsigned short* __restrict__ O1) {
    __shared__ unsigned short Ax[16 * 512];
    __shared__ unsigned short Wl[8192];
    int b = blockIdx.x;
    if (b < nb0) gatepair_body(X0, W10, b10, W20, b20, O0, b, Ax, Wl);
    else         gatepair_body(X1, W11, b11, W21, b21, O1, b - nb0, Ax, Wl);
}

// ---------------- CSR gather-aggregation body (prescaled y', 64-ch wave tasks) --------
// out[v] = relu(dinv[v]*(y'[v] + sum_s y'[s]) + bias); nch64 = C/64 chunks per node
__device__ __forceinline__ void gagg_body(const unsigned short* __restrict__ y,
                                          const int* __restrict__ ptr,
                                          const int* __restrict__ esrc,
                                          const float* __restrict__ dinv,
                                          const float* __restrict__ bias,
                                          unsigned short* __restrict__ ob,
                                          int idx, int nch64, int lane) {
    int v = idx / nch64, ch = idx - v * nch64;
    int C = nch64 << 6;
    int c0 = (ch << 6) + lane;
    float a0 = bf2f(y[(size_t)v * C + c0]);
    int e = ptr[v], e1 = ptr[v + 1];
    for (; e + 3 < e1; e += 4) {
        int s0 = esrc[e], s1 = esrc[e + 1], s2 = esrc[e + 2], s3 = esrc[e + 3];
        float x0 = bf2f(y[(size_t)s0 * C + c0]);
        float x1 = bf2f(y[(size_t)s1 * C + c0]);
        float x2 = bf2f(y[(size_t)s2 * C + c0]);
        float x3 = bf2f(y[(size_t)s3 * C + c0]);
        a0 += (x0 + x1) + (x2 + x3);
    }
    for (; e < e1; ++e)
        a0 += bf2f(y[(size_t)esrc[e] * C + c0]);
    float dv = dinv[v];
    ob[(size_t)v * C + c0] = f2bf(fmaxf(dv * a0 + bias[c0], 0.f));
}

// fused gagg: wave-tasks [0, N0*nch0) set 0, rest set 1
__global__ __launch_bounds__(256) void k_gagg2(
        const unsigned short* __restrict__ y0, const int* __restrict__ ptr0,
        const int* __restrict__ esrc0, const float* __restrict__ dinv0,
        const float* __restrict__ bias0, unsigned short* __restrict__ ob0, int N0, int nch0,
        const unsigned short* __restrict__ y1, const int* __restrict__ ptr1,
        const int* __restrict__ esrc1, const float* __restrict__ dinv1,
        const float* __restrict__ bias1, unsigned short* __restrict__ ob1, int N1, int nch1) {
    int idx = blockIdx.x * 4 + (threadIdx.x >> 6);
    int lane = threadIdx.x & 63;
    int T0 = N0 * nch0;
    if (idx < T0) gagg_body(y0, ptr0, esrc0, dinv0, bias0, ob0, idx, nch0, lane);
    else {
        idx -= T0;
        if (idx < N1 * nch1) gagg_body(y1, ptr1, esrc1, dinv1, bias1, ob1, idx, nch1, lane);
    }
}

// ---------------- tweet attention pooling (S=30, bf16 in, bf16 out) ----------------
__global__ __launch_bounds__(128) void k_attpool(const unsigned short* __restrict__ x,
                                                 const unsigned short* __restrict__ gate,
                                                 unsigned short* __restrict__ outb, int S) {
    int seg = blockIdx.x;
    int c = threadIdx.x;
    size_t base = (size_t)seg * S * 128 + c;
    float m = -1e30f;
    for (int n = 0; n < S; ++n) m = fmaxf(m, bf2f(gate[base + (size_t)n * 128]));
    float se = 0.f, acc = 0.f;
    for (int n = 0; n < S; ++n) {
        float g = bf2f(gate[base + (size_t)n * 128]);
        float e = expf(g - m);
        se += e;
        acc += e * bf2f(x[base + (size_t)n * 128]);
    }
    outb[(size_t)seg * 128 + c] = f2bf(acc / (se + 1e-16f));
}

// ---------------- user attention pooling: chunked 3-stage (S=625, bf16 in) -------------
__global__ __launch_bounds__(256) void k_pool_pmax(const unsigned short* __restrict__ gate,
                                                   float* __restrict__ pmax, int S) {
    int seg = blockIdx.x, ch = blockIdx.y;
    int c = threadIdx.x & 127, j = threadIdx.x >> 7;
    int csz = (S + NCHUNK - 1) / NCHUNK;
    int n0 = ch * csz, n1 = min(S, n0 + csz);
    size_t base = (size_t)seg * S * 128 + c;
    float m = -1e30f;
    for (int n = n0 + j; n < n1; n += 2)
        m = fmaxf(m, bf2f(gate[base + (size_t)n * 128]));
    __shared__ float red[2][128];
    red[j][c] = m;
    __syncthreads();
    if (j == 0)
        pmax[((size_t)seg * NCHUNK + ch) * 128 + c] = fmaxf(red[0][c], red[1][c]);
}

__global__ __launch_bounds__(256) void k_pool_psum(const unsigned short* __restrict__ x,
                                                   const unsigned short* __restrict__ gate,
                                                   const float* __restrict__ pmax,
                                                   float* __restrict__ pse,
                                                   float* __restrict__ pacc, int S) {
    int seg = blockIdx.x, ch = blockIdx.y;
    int c = threadIdx.x & 127, j = threadIdx.x >> 7;
    int csz = (S + NCHUNK - 1) / NCHUNK;
    int n0 = ch * csz, n1 = min(S, n0 + csz);
    size_t base = (size_t)seg * S * 128 + c;
    float m = -1e30f;
#pragma unroll
    for (int ch2 = 0; ch2 < NCHUNK; ++ch2)
        m = fmaxf(m, pmax[((size_t)seg * NCHUNK + ch2) * 128 + c]);
    float se = 0.f, acc = 0.f;
    for (int n = n0 + j; n < n1; n += 2) {
        float g = bf2f(gate[base + (size_t)n * 128]);
        float e = expf(g - m);
        se += e;
        acc += e * bf2f(x[base + (size_t)n * 128]);
    }
    __shared__ float rs[2][128], ra[2][128];
    rs[j][c] = se; ra[j][c] = acc;
    __syncthreads();
    if (j == 0) {
        size_t o = ((size_t)seg * NCHUNK + ch) * 128 + c;
        pse[o]  = rs[0][c] + rs[1][c];
        pacc[o] = ra[0][c] + ra[1][c];
    }
}

__global__ __launch_bounds__(128) void k_pool_final(const float* __restrict__ pse,
                                                    const float* __restrict__ pacc,
                                                    float* __restrict__ out) {
    int seg = blockIdx.x, c = threadIdx.x;
    float se = 0.f, acc = 0.f;
    for (int ch = 0; ch < NCHUNK; ++ch) {
        size_t o = ((size_t)seg * NCHUNK + ch) * 128 + c;
        se += pse[o];
        acc += pacc[o];
    }
    out[(size_t)seg * 128 + c] = acc / (se + 1e-16f);
}

// ---------------- GRU recurrence (gi fp32 precomputed): 64 blocks x 768 threads --------
__global__ __launch_bounds__(768) void k_gru_rec(const float* __restrict__ gi,
                                                 const float* __restrict__ whhT,  // [128][384]
                                                 const float* __restrict__ bhh,
                                                 float* __restrict__ hT) {
    __shared__ float hs[128];
    __shared__ float ph[768];
    int b = blockIdx.x, t = threadIdx.x;
    int half = (t >= 384) ? 1 : 0;
    int j = t - half * 384;
    float w[64];
#pragma unroll
    for (int i = 0; i < 64; ++i)
        w[i] = whhT[(half * 64 + i) * 384 + j];
    float chr = 0.f, chz = 0.f, chn = 0.f;
    if (t < 128) {
        hs[t] = 0.f;
        chr = bhh[t]; chz = bhh[128 + t]; chn = bhh[256 + t];
    }
    __syncthreads();
    for (int step = 0; step < TT; ++step) {
        float a0 = 0.f, a1 = 0.f, a2 = 0.f, a3 = 0.f;
        const float* hbase = hs + half * 64;
#pragma unroll
        for (int i = 0; i < 64; i += 4) {
            float4 hv = *(const float4*)(hbase + i);
            a0 += hv.x * w[i + 0];
            a1 += hv.y * w[i + 1];
            a2 += hv.z * w[i + 2];
            a3 += hv.w * w[i + 3];
        }
        ph[t] = (a0 + a1) + (a2 + a3);
        __syncthreads();
        float hnew = 0.f;
        if (t < 128) {
            const float* girow = gi + ((size_t)b * TT + step) * 384;
            float hr = ph[t] + ph[t + 384] + chr;
            float hz = ph[128 + t] + ph[512 + t] + chz;
            float hn = ph[256 + t] + ph[640 + t] + chn;
            float ir = girow[t], iz = girow[128 + t], in = girow[256 + t];
            float r = 1.f / (1.f + expf(-(ir + hr)));
            float z = 1.f / (1.f + expf(-(iz + hz)));
            float n = tanhf(in + r * hn);
            hnew = (1.f - z) * n + z * hs[t];
        }
        __syncthreads();
        if (t < 128) hs[t] = hnew;
        __syncthreads();
    }
    if (t < 128) hT[(size_t)b * 128 + t] = hs[t];
}

// ---------------- head MLP ----------------
__global__ __launch_bounds__(256) void k_head(const float* __restrict__ uf,
                                              const float* __restrict__ up,
                                              const float* __restrict__ th,
                                              const float* __restrict__ Wd0, const float* __restrict__ bd0,
                                              const float* __restrict__ Wd1, const float* __restrict__ bd1,
                                              const float* __restrict__ Wp, const float* __restrict__ bp,
                                              float* __restrict__ out) {
    __shared__ float in0[288], l1[256], l2[64];
    int b = blockIdx.x, t = threadIdx.x;
    if (t < 32) in0[t] = uf[b * 32 + t];
    else if (t < 160) in0[t] = up[b * 128 + (t - 32)];
    if (t < 128) in0[160 + t] = th[b * 128 + t];
    __syncthreads();
    float acc = bd0[t];
    for (int k = 0; k < 288; ++k) acc += in0[k] * Wd0[k * 256 + t];
    l1[t] = fmaxf(acc, 0.f);
    __syncthreads();
    if (t < 64) {
        float a2 = bd1[t];
        for (int k = 0; k < 256; ++k) a2 += l1[k] * Wd1[k * 64 + t];
        l2[t] = fmaxf(a2, 0.f);
    }
    __syncthreads();
    if (t < 64) {
        float p = l2[t] * Wp[t];
        for (int off = 32; off; off >>= 1) p += __shfl_down(p, off, 64);
        if (t == 0) out[b] = 1.f / (1.f + expf(-(p + bp[0])));
    }
}

// ---------------- launch ----------------
extern "C" void kernel_launch(void* const* d_in, const int* in_sizes, int n_in,
                              void* d_out, int out_size, void* d_ws, size_t ws_size,
                              hipStream_t stream) {
    const float* user_x     = (const float*)d_in[0];
    const float* user_feats = (const float*)d_in[1];
    const float* tweet_x    = (const float*)d_in[2];
    const float* Wu0 = (const float*)d_in[3];  const float* bu0 = (const float*)d_in[4];
    const float* Wu1 = (const float*)d_in[5];  const float* bu1 = (const float*)d_in[6];
    const float* Wgu1 = (const float*)d_in[7]; const float* bgu1 = (const float*)d_in[8];
    const float* Wgu2 = (const float*)d_in[9]; const float* bgu2 = (const float*)d_in[10];
    const float* Wt0 = (const float*)d_in[11]; const float* bt0 = (const float*)d_in[12];
    const float* Wt1 = (const float*)d_in[13]; const float* bt1 = (const float*)d_in[14];
    const float* Wgt1 = (const float*)d_in[15]; const float* bgt1 = (const float*)d_in[16];
    const float* Wgt2 = (const float*)d_in[17]; const float* bgt2 = (const float*)d_in[18];
    const float* W_ih = (const float*)d_in[19]; const float* b_ih = (const float*)d_in[20];
    const float* W_hh = (const float*)d_in[21]; const float* b_hh = (const float*)d_in[22];
    const float* Wd0 = (const float*)d_in[23]; const float* bd0 = (const float*)d_in[24];
    const float* Wd1 = (const float*)d_in[25]; const float* bd1 = (const float*)d_in[26];
    const float* Wp  = (const float*)d_in[27]; const float* bp  = (const float*)d_in[28];
    const int* ue = (const int*)d_in[29];
    const int* te = (const int*)d_in[30];
    const int* ue_src = ue, *ue_dst = ue + EU;
    const int* te_src = te, *te_dst = te + NTE;

    // ---- workspace layout ----
    float* ws = (float*)d_ws;
    size_t o = 0;
    float* dinv_u = ws + o;     o += NU;
    float* dinv_t = ws + o;     o += NTNODES;       // contiguous after dinv_u
    float* user_pool = ws + o;  o += (size_t)BB * 128;
    float* tweet_h = ws + o;    o += (size_t)BB * 128;
    float* whhT = ws + o;       o += 128 * 384;
    float* gi = ws + o;         o += (size_t)NSEG_T * 384;
    float* pmax = ws + o;       o += 131072;
    float* pse = ws + o;        o += 131072;
    float* pacc = ws + o;       o += 131072;
    int* iw = (int*)(ws + o);
    int* hist_u = iw;
    int* hist_t = iw + NU;
    int* ptr_u  = iw + NU + NTNODES;
    int* fill_u = ptr_u + NU + 1;
    int* esrc_u = fill_u + NU;
    int* ptr_t  = esrc_u + EU;
    int* fill_t = ptr_t + NTNODES + 1;
    int* esrc_t = fill_t + NTNODES;
    int* bsum_u = esrc_t + NTE;
    int* bsum_t = bsum_u + 256;
    unsigned short* pk = (unsigned short*)(((uintptr_t)(bsum_t + 256) + 15) & ~(uintptr_t)15);
    unsigned short* pWu0  = pk;
    unsigned short* pWu1  = pWu0  + 16384;
    unsigned short* pWgu1 = pWu1  + 16384;
    unsigned short* pWgu2 = pWgu1 + 16384;
    unsigned short* pWt0  = pWgu2 + 16384;
    unsigned short* pWt1  = pWt0  + 196608;
    unsigned short* pWgt1 = pWt1  + 32768;
    unsigned short* pWgt2 = pWgt1 + 16384;
    unsigned short* pWih  = pWgt2 + 16384;
    // bf16 arena: 4 slots of NT*256 halfwords
    unsigned short* arena = (unsigned short*)(((uintptr_t)(pWih + 49152) + 15) & ~(uintptr_t)15);
    const size_t SLOT = (size_t)NTNODES * 256;      // 7,864,320 hw
    unsigned short* P0 = arena;
    unsigned short* P1 = P0 + SLOT;
    unsigned short* P2 = P1 + SLOT;
    unsigned short* P3 = P2 + SLOT;
    unsigned short* tpool_bf = P3 + SLOT;           // 1024*128 hw
    float* out = (float*)d_out;

    dim3 b256(256);
    const float* ND = nullptr;

    // ---- packs + whh transpose ----
    hipLaunchKernelGGL(k_packall, dim3((425984 + 255) / 256), b256, 0, stream,
                       Wu0, Wu1, Wgu1, Wgu2, Wt0, Wt1, Wgt1, Wgt2, W_ih, W_hh, whhT, pk);

    // ---- degrees + CSR (fused user+tweet) ----
    hipLaunchKernelGGL(k_zeroint, dim3((NU + NTNODES + 255) / 256), b256, 0, stream,
                       hist_u, NU + NTNODES);
    hipLaunchKernelGGL(k_hist2, dim3((EU + NTE + 255) / 256), b256, 0, stream,
                       ue_dst, te_dst, hist_u, hist_t);
    hipLaunchKernelGGL(k_scan_a2, dim3(NBU + NBT), b256, 0, stream, hist_u, bsum_u, bsum_t);
    hipLaunchKernelGGL(k_scan_b2, dim3(2), b256, 0, stream, bsum_u, bsum_t);
    hipLaunchKernelGGL(k_scan_c2, dim3(NBU + NBT), b256, 0, stream,
                       hist_u, bsum_u, bsum_t, ptr_u, fill_u, ptr_t, fill_t, dinv_u);
    hipLaunchKernelGGL(k_place2, dim3((EU + NTE + 255) / 256), b256, 0, stream,
                       ue_src, ue_dst, te_src, te_dst, fill_u, esrc_u, fill_t, esrc_t);

    // ---- J1: tweet conv1 (fp32 A, bn 0-1 -> P0) + user gemm1 (fp32 A, bn 2 -> P2) ----
    hipLaunchKernelGGL(HIP_KERNEL_NAME(k_mgemm_dual<true>), dim3(NU / 32, 3), b256, 0, stream,
                       (const void*)tweet_x, pWt0, dinv_t, (void*)P0, NTNODES, 768, 256,
                       (const void*)user_x,  pWu0, dinv_u, (void*)P2, NU,      128, 128,
                       2);
    // ---- J2: tweet gagg1 (P0 -> h1t@P1, nch64=4) + user gagg1 (P2 -> h1u@P3, nch64=2) ----
    hipLaunchKernelGGL(k_gagg2, dim3((NTNODES * 4 + NU * 2 + 3) / 4), b256, 0, stream,
                       P0, ptr_t, esrc_t, dinv_t, bt0, P1, NTNODES, 4,
                       P2, ptr_u, esrc_u, dinv_u, bu0, P3, NU, 2);
    // ---- J3: tweet gemm2 (h1t@P1 -> y2t'@P2) + user gemm2 (h1u@P3 -> y2u'@P0) ----
    hipLaunchKernelGGL(HIP_KERNEL_NAME(k_mgemm_dual<false>), dim3(NU / 32, 2), b256, 0, stream,
                       (const void*)P1, pWt1, dinv_t, (void*)P2, NTNODES, 256, 128,
                       (const void*)P3, pWu1, dinv_u, (void*)P0, NU,      128, 128,
                       1);
    // ---- J4: tweet gagg2 (P2 -> g2t@P1) + user gagg2 (P0 -> h2u@P3), nch64=2 each ----
    hipLaunchKernelGGL(k_gagg2, dim3(((NTNODES + NU) * 2 + 3) / 4), b256, 0, stream,
                       P2, ptr_t, esrc_t, dinv_t, bt1, P1, NTNODES, 2,
                       P0, ptr_u, esrc_u, dinv_u, bu1, P3, NU, 2);
    // ---- J5: user gatepair (h2u@P3 -> gate_u@P0) + tweet gatepair (g2t@P1 -> gate_t@P2) ----
    hipLaunchKernelGGL(k_gatepair2, dim3(NU / 64 + NTNODES / 64), b256, 0, stream,
                       P3, pWgu1, bgu1, pWgu2, bgu2, P0, NU / 64,
                       P1, pWgt1, bgt1, pWgt2, bgt2, P2);

    // ---- pools ----
    hipLaunchKernelGGL(k_pool_pmax, dim3(BB, NCHUNK), b256, 0, stream, P0, pmax, NU / BB);
    hipLaunchKernelGGL(k_pool_psum, dim3(BB, NCHUNK), b256, 0, stream,
                       P3, P0, pmax, pse, pacc, NU / BB);
    hipLaunchKernelGGL(k_pool_final, dim3(BB), dim3(128), 0, stream, pse, pacc, user_pool);
    hipLaunchKernelGGL(k_attpool, dim3(NSEG_T), dim3(128), 0, stream,
                       P1, P2, tpool_bf, NW);

    // ---- GRU: gi = tweet_pool @ W_ih^T + b_ih (fp32 out) ----
    hipLaunchKernelGGL(HIP_KERNEL_NAME(k_mgemm<false>), dim3(NSEG_T / 32, 3), b256, 0, stream,
                       (const void*)tpool_bf, pWih, b_ih, ND, (void*)gi, NSEG_T, 128, 384, 5);
    hipLaunchKernelGGL(k_gru_rec, dim3(BB), dim3(768), 0, stream,
                       gi, whhT, b_hh, tweet_h);

    // ---- head ----
    hipLaunchKernelGGL(k_head, dim3(BB), b256, 0, stream,
                       user_feats, user_pool, tweet_h,
                       Wd0, bd0, Wd1, bd1, Wp, bp, out);
}

// Round 15
// 327.555 us; speedup vs baseline: 1.2640x; 1.2640x over previous
//
#include <hip/hip_runtime.h>
#include <hip/hip_bf16.h>

// ---------------- problem constants ----------------
#define NU 40000
#define EU 640000
#define BB 64
#define TT 16
#define NW 30
#define NTNODES 30720       // B*T*NW
#define NTE 61440           // tweet edges
#define NSEG_T 1024         // B*T
#define NCHUNK 16           // chunks per user segment for att-pool
#define NBU 157             // ceil(NU/256)
#define NBT 120             // NTNODES/256

typedef __attribute__((ext_vector_type(8))) short bf16x8;
typedef __attribute__((ext_vector_type(4))) float f32x4;

__device__ __forceinline__ unsigned short f2bf(float x) {
    union { float f; unsigned u; } v; v.f = x;
    unsigned r = v.u + 0x7FFFu + ((v.u >> 16) & 1u);   // RNE
    return (unsigned short)(r >> 16);
}
__device__ __forceinline__ float bf2f(unsigned short u) {
    union { unsigned u; float f; } v; v.u = (unsigned)u << 16; return v.f;
}
// async 16B global->LDS (per-lane global src; LDS dest = wave-uniform base + lane*16)
__device__ __forceinline__ void gld16(const unsigned short* g, unsigned short* l) {
    __builtin_amdgcn_global_load_lds(
        (const __attribute__((address_space(1))) void*)g,
        (__attribute__((address_space(3))) void*)l, 16, 0, 0);
}

// ---------------- degree / CSR build (fused user+tweet) ----------------
__global__ void k_zeroint(int* __restrict__ p, int n) {
    int i = blockIdx.x * blockDim.x + threadIdx.x;
    if (i < n) p[i] = 0;
}

__global__ void k_hist2(const int* __restrict__ ue_dst, const int* __restrict__ te_dst,
                        int* __restrict__ hist_u, int* __restrict__ hist_t) {
    int i = blockIdx.x * blockDim.x + threadIdx.x;
    if (i < EU) atomicAdd(&hist_u[ue_dst[i]], 1);
    else if (i < EU + NTE) atomicAdd(&hist_t[te_dst[i - EU]], 1);
}

__global__ __launch_bounds__(256) void k_scan_a2(const int* __restrict__ hist_u,
                                                 int* __restrict__ bsum_u,
                                                 int* __restrict__ bsum_t) {
    __shared__ int red[256];
    int b = blockIdx.x, t = threadIdx.x;
    const int* h; int* bs; int n, lb;
    if (b < NBU) { h = hist_u;      bs = bsum_u; n = NU;      lb = b; }
    else         { h = hist_u + NU; bs = bsum_t; n = NTNODES; lb = b - NBU; }
    int i = lb * 256 + t;
    red[t] = (i < n) ? h[i] : 0;
    __syncthreads();
    for (int off = 128; off; off >>= 1) {
        if (t < off) red[t] += red[t + off];
        __syncthreads();
    }
    if (t == 0) bs[lb] = red[0];
}

__global__ __launch_bounds__(256) void k_scan_b2(int* __restrict__ bsum_u,
                                                 int* __restrict__ bsum_t) {
    __shared__ int s[256];
    int t = threadIdx.x;
    int* bs = blockIdx.x ? bsum_t : bsum_u;
    int nb  = blockIdx.x ? NBT : NBU;
    s[t] = (t < nb) ? bs[t] : 0;
    __syncthreads();
    for (int off = 1; off < 256; off <<= 1) {
        int v = (t >= off) ? s[t - off] : 0;
        __syncthreads();
        s[t] += v;
        __syncthreads();
    }
    if (t < nb) bs[t] = (t == 0) ? 0 : s[t - 1];
}

__global__ __launch_bounds__(256) void k_scan_c2(const int* __restrict__ hist_u,
                                                 const int* __restrict__ bsum_u,
                                                 const int* __restrict__ bsum_t,
                                                 int* __restrict__ ptr_u, int* __restrict__ fill_u,
                                                 int* __restrict__ ptr_t, int* __restrict__ fill_t,
                                                 float* __restrict__ dinv_u) {
    __shared__ int s[256];
    int b = blockIdx.x, t = threadIdx.x;
    const int *h, *bs; int *ptr, *fill; int n, lb; float* dv;
    if (b < NBU) { h = hist_u;      bs = bsum_u; ptr = ptr_u; fill = fill_u; n = NU;      lb = b;       dv = dinv_u; }
    else         { h = hist_u + NU; bs = bsum_t; ptr = ptr_t; fill = fill_t; n = NTNODES; lb = b - NBU; dv = dinv_u + NU; }
    int i = lb * 256 + t;
    int hv = (i < n) ? h[i] : 0;
    s[t] = hv;
    __syncthreads();
    for (int off = 1; off < 256; off <<= 1) {
        int v = (t >= off) ? s[t - off] : 0;
        __syncthreads();
        s[t] += v;
        __syncthreads();
    }
    if (i < n) {
        int excl = bs[lb] + s[t] - hv;
        ptr[i] = excl;
        fill[i] = excl;
        dv[i] = rsqrtf((float)hv + 1.0f);
        if (i == n - 1) ptr[n] = excl + hv;
    }
}

__global__ void k_place2(const int* __restrict__ ue_src, const int* __restrict__ ue_dst,
                         const int* __restrict__ te_src, const int* __restrict__ te_dst,
                         int* __restrict__ fill_u, int* __restrict__ esrc_u,
                         int* __restrict__ fill_t, int* __restrict__ esrc_t) {
    int e = blockIdx.x * blockDim.x + threadIdx.x;
    if (e < EU) {
        int pos = atomicAdd(&fill_u[ue_dst[e]], 1);
        esrc_u[pos] = ue_src[e];
    } else if (e < EU + NTE) {
        int e2 = e - EU;
        int pos = atomicAdd(&fill_t[te_dst[e2]], 1);
        esrc_t[pos] = te_src[e2];
    }
}

// ---------------- weight pre-pack (9 weights + W_hh transpose, one kernel) ------------
__device__ __forceinline__ void pack_one(const float* __restrict__ W,
                                         unsigned short* __restrict__ out,
                                         int f, int K, int N, int trans) {
    int j = f & 7;
    int chunk = f >> 3;
    int c = chunk & 511;
    int panel = chunk >> 9;
    int KS = K >> 5;
    int ks = panel % KS;
    int bn = panel / KS;
    int n = bn * 128 + (c & 127);
    int k = ks * 32 + (c >> 7) * 8 + j;
    float v = trans ? W[(size_t)n * K + k] : W[(size_t)k * N + n];
    out[f] = f2bf(v);
}

__global__ void k_packall(const float* __restrict__ Wu0, const float* __restrict__ Wu1,
                          const float* __restrict__ Wgu1, const float* __restrict__ Wgu2,
                          const float* __restrict__ Wt0, const float* __restrict__ Wt1,
                          const float* __restrict__ Wgt1, const float* __restrict__ Wgt2,
                          const float* __restrict__ Wih,
                          const float* __restrict__ Whh, float* __restrict__ whhT,
                          unsigned short* __restrict__ pk) {
    int f = blockIdx.x * blockDim.x + threadIdx.x;
    if (f < 16384)        pack_one(Wu0,  pk + 0,      f,          128, 128, 0);
    else if (f < 32768)   pack_one(Wu1,  pk + 16384,  f - 16384,  128, 128, 0);
    else if (f < 49152)   pack_one(Wgu1, pk + 32768,  f - 32768,  128, 128, 0);
    else if (f < 65536)   pack_one(Wgu2, pk + 49152,  f - 49152,  128, 128, 0);
    else if (f < 262144)  pack_one(Wt0,  pk + 65536,  f - 65536,  768, 256, 0);
    else if (f < 294912)  pack_one(Wt1,  pk + 262144, f - 262144, 256, 128, 0);
    else if (f < 311296)  pack_one(Wgt1, pk + 294912, f - 294912, 128, 128, 0);
    else if (f < 327680)  pack_one(Wgt2, pk + 311296, f - 311296, 128, 128, 0);
    else if (f < 376832)  pack_one(Wih,  pk + 327680, f - 327680, 128, 384, 1);
    else if (f < 425984) {                          // W_hh [384][128] -> whhT [128][384]
        int j2 = f - 376832;
        int r = j2 >> 7, k2 = j2 & 127;
        whhT[k2 * 384 + r] = Whh[j2];
    }
}

// ---------------- bf16 MFMA GEMM body, BM=32 BN=128 BK=64 ----------------
// AF32: A fp32 (reg-staged+convert, padded planes). !AF32: A bf16 (global_load_lds).
// flags: 1=bias, 2=relu, 4=fp32 out. dscale: if non-null, C row scaled (pre-bias).
// M%32==0, K%64==0, N%128==0.
template<bool AF32>
__device__ __forceinline__ void mgemm_body(const void* __restrict__ Araw,
                                           const unsigned short* __restrict__ Bpk,
                                           const float* __restrict__ bias,
                                           const float* __restrict__ dscale,
                                           void* __restrict__ Craw,
                                           int M, int K, int N, int flags,
                                           int bm, int bn,
                                           unsigned short* Alds, unsigned short* Blds) {
    constexpr int AST = AF32 ? 260 : 256;
    int tid = threadIdx.x, lane = tid & 63, w = tid >> 6;
    int wr = (w >> 1) * 16, wc = (w & 1) * 64;
    int l15 = lane & 15, lk = lane >> 4;

    f32x4 acc[4];
#pragma unroll
    for (int n = 0; n < 4; ++n) acc[n] = (f32x4){0.f, 0.f, 0.f, 0.f};

    const unsigned short* Bpanel = Bpk + (size_t)bn * (K >> 5) * 4096;
    int KS64 = K >> 6;

    for (int ks = 0; ks < KS64; ++ks) {
        int k0 = ks * 64;
        {
            const unsigned short* bg = Bpanel + (size_t)ks * 8192;
#pragma unroll
            for (int q = 0; q < 4; ++q) {
                int off = (w * 4 + q) * 512;
                gld16(bg + off + lane * 8, &Blds[off]);
            }
        }
        if (AF32) {
            const float* A = (const float*)Araw;
#pragma unroll
            for (int p = 0; p < 2; ++p) {
                int f4 = p * 256 + tid;
                int row = f4 >> 4;
                int kq  = f4 & 15;
                float4 av = *(const float4*)(A + (size_t)(bm * 32 + row) * K + k0 + kq * 4);
                unsigned lo = (unsigned)f2bf(av.x) | ((unsigned)f2bf(av.y) << 16);
                unsigned hi = (unsigned)f2bf(av.z) | ((unsigned)f2bf(av.w) << 16);
                int off = (kq >> 1) * AST + row * 8 + (kq & 1) * 4;
                *(uint2*)&Alds[off] = make_uint2(lo, hi);
            }
        } else {
            const unsigned short* A = (const unsigned short*)Araw;
            int kblk = 2 * w + (lane >> 5);
            int row = lane & 31;
            gld16(A + (size_t)(bm * 32 + row) * K + k0 + kblk * 8,
                  &Alds[w * 512]);
        }
        __syncthreads();
#pragma unroll
        for (int h = 0; h < 2; ++h) {
            int kb = h * 4 + lk;
            bf16x8 a = *(const bf16x8*)&Alds[kb * AST + (wr + l15) * 8];
            bf16x8 b[4];
#pragma unroll
            for (int n = 0; n < 4; ++n)
                b[n] = *(const bf16x8*)&Blds[kb * 1024 + (wc + n * 16 + l15) * 8];
#pragma unroll
            for (int n = 0; n < 4; ++n)
                acc[n] = __builtin_amdgcn_mfma_f32_16x16x32_bf16(a, b[n], acc[n], 0, 0, 0);
        }
        __syncthreads();
    }

    int grow0 = bm * 32 + wr + lk * 4;
#pragma unroll
    for (int i = 0; i < 4; ++i) {
        int grow = grow0 + i;
        float ds = dscale ? dscale[grow] : 1.f;
#pragma unroll
        for (int n = 0; n < 4; ++n) {
            int gcol = bn * 128 + wc + n * 16 + l15;
            float v = acc[n][i] * ds;
            if (flags & 1) v += bias[gcol];
            if (flags & 2) v = fmaxf(v, 0.f);
            if (flags & 4) ((float*)Craw)[(size_t)grow * N + gcol] = v;
            else ((unsigned short*)Craw)[(size_t)grow * N + gcol] = f2bf(v);
        }
    }
}

template<bool AF32>
__global__ __launch_bounds__(256) void k_mgemm(const void* __restrict__ Araw,
                                               const unsigned short* __restrict__ Bpk,
                                               const float* __restrict__ bias,
                                               const float* __restrict__ dscale,
                                               void* __restrict__ Craw,
                                               int M, int K, int N, int flags) {
    constexpr int AST = AF32 ? 260 : 256;
    __shared__ unsigned short Alds[8 * AST];
    __shared__ unsigned short Blds[8192];
    if (blockIdx.x * 32 >= M) return;
    mgemm_body<AF32>(Araw, Bpk, bias, dscale, Craw, M, K, N, flags,
                     blockIdx.x, blockIdx.y, Alds, Blds);
}

// dual GEMM: grid.y in [0,bnSplit) -> set 0, [bnSplit,..) -> set 1
template<bool AF32>
__global__ __launch_bounds__(256) void k_mgemm_dual(
        const void* __restrict__ A0, const unsigned short* __restrict__ B0,
        const float* __restrict__ ds0, void* __restrict__ C0, int M0, int K0, int N0,
        const void* __restrict__ A1, const unsigned short* __restrict__ B1,
        const float* __restrict__ ds1, void* __restrict__ C1, int M1, int K1, int N1,
        int bnSplit) {
    constexpr int AST = AF32 ? 260 : 256;
    __shared__ unsigned short Alds[8 * AST];
    __shared__ unsigned short Blds[8192];
    int bn = blockIdx.y, bm = blockIdx.x;
    if (bn < bnSplit) {
        if (bm * 32 >= M0) return;
        mgemm_body<AF32>(A0, B0, (const float*)nullptr, ds0, C0, M0, K0, N0, 0,
                         bm, bn, Alds, Blds);
    } else {
        if (bm * 32 >= M1) return;
        mgemm_body<AF32>(A1, B1, (const float*)nullptr, ds1, C1, M1, K1, N1, 0,
                         bm, bn - bnSplit, Alds, Blds);
    }
}

// ---------------- fused gate pair body: out = (X@W1+b1)@W2+b2, K=N=128 ---------------
__device__ __forceinline__ void gatepair_body(const unsigned short* __restrict__ X,
                                              const unsigned short* __restrict__ W1,
                                              const float* __restrict__ b1,
                                              const unsigned short* __restrict__ W2,
                                              const float* __restrict__ b2,
                                              unsigned short* __restrict__ outp,
                                              int bm,
                                              unsigned short* Ax, unsigned short* Wl) {
    int tid = threadIdx.x, lane = tid & 63, w = tid >> 6;
    int wr = (w >> 1) * 32, wc = (w & 1) * 64;
    int l15 = lane & 15, lk = lane >> 4;

#pragma unroll
    for (int q = 0; q < 4; ++q) {
        int pl = w * 4 + q;
        gld16(X + (size_t)(bm * 64 + lane) * 128 + pl * 8, &Ax[pl * 512]);
    }

    f32x4 acc[2][4];
#pragma unroll
    for (int m = 0; m < 2; ++m)
#pragma unroll
        for (int n = 0; n < 4; ++n) acc[m][n] = (f32x4){0.f, 0.f, 0.f, 0.f};

    for (int ks = 0; ks < 2; ++ks) {
        const unsigned short* wp = W1 + ks * 8192;
#pragma unroll
        for (int q = 0; q < 4; ++q) {
            int off = (w * 4 + q) * 512;
            gld16(wp + off + lane * 8, &Wl[off]);
        }
        __syncthreads();
#pragma unroll
        for (int h = 0; h < 2; ++h) {
            int kb = h * 4 + lk;
            bf16x8 a[2], b[4];
#pragma unroll
            for (int m = 0; m < 2; ++m)
                a[m] = *(const bf16x8*)&Ax[(ks * 8 + kb) * 512 + (wr + m * 16 + l15) * 8];
#pragma unroll
            for (int n = 0; n < 4; ++n)
                b[n] = *(const bf16x8*)&Wl[kb * 1024 + (wc + n * 16 + l15) * 8];
#pragma unroll
            for (int m = 0; m < 2; ++m)
#pragma unroll
                for (int n = 0; n < 4; ++n)
                    acc[m][n] = __builtin_amdgcn_mfma_f32_16x16x32_bf16(a[m], b[n], acc[m][n], 0, 0, 0);
        }
        __syncthreads();
    }

#pragma unroll
    for (int m = 0; m < 2; ++m)
#pragma unroll
        for (int n = 0; n < 4; ++n) {
            int col = wc + n * 16 + l15;
            float bv = b1[col];
#pragma unroll
            for (int i = 0; i < 4; ++i) {
                int row = wr + m * 16 + lk * 4 + i;
                float v = acc[m][n][i] + bv;     // NO relu (Linear->Linear)
                Ax[(col >> 3) * 512 + row * 8 + (col & 7)] = f2bf(v);
            }
        }
    __syncthreads();

#pragma unroll
    for (int m = 0; m < 2; ++m)
#pragma unroll
        for (int n = 0; n < 4; ++n) acc[m][n] = (f32x4){0.f, 0.f, 0.f, 0.f};
    for (int ks = 0; ks < 2; ++ks) {
        const unsigned short* wp = W2 + ks * 8192;
#pragma unroll
        for (int q = 0; q < 4; ++q) {
            int off = (w * 4 + q) * 512;
            gld16(wp + off + lane * 8, &Wl[off]);
        }
        __syncthreads();
#pragma unroll
        for (int h = 0; h < 2; ++h) {
            int kb = h * 4 + lk;
            bf16x8 a[2], b[4];
#pragma unroll
            for (int m = 0; m < 2; ++m)
                a[m] = *(const bf16x8*)&Ax[(ks * 8 + kb) * 512 + (wr + m * 16 + l15) * 8];
#pragma unroll
            for (int n = 0; n < 4; ++n)
                b[n] = *(const bf16x8*)&Wl[kb * 1024 + (wc + n * 16 + l15) * 8];
#pragma unroll
            for (int m = 0; m < 2; ++m)
#pragma unroll
                for (int n = 0; n < 4; ++n)
                    acc[m][n] = __builtin_amdgcn_mfma_f32_16x16x32_bf16(a[m], b[n], acc[m][n], 0, 0, 0);
        }
        __syncthreads();
    }

#pragma unroll
    for (int m = 0; m < 2; ++m)
#pragma unroll
        for (int n = 0; n < 4; ++n) {
            int col = wc + n * 16 + l15;
            float bv = b2[col];
#pragma unroll
            for (int i = 0; i < 4; ++i) {
                int row = bm * 64 + wr + m * 16 + lk * 4 + i;
                float v = acc[m][n][i] + bv;     // NO relu
                outp[(size_t)row * 128 + col] = f2bf(v);
            }
        }
}

// fused: blocks [0,nb0) set 0, [nb0, ...) set 1
__global__ __launch_bounds__(256) void k_gatepair2(
        const unsigned short* __restrict__ X0, const unsigned short* __restrict__ W10,
        const float* __restrict__ b10, const unsigned short* __restrict__ W20,
        const float* __restrict__ b20, unsigned short* __restrict__ O0, int nb0,
        const unsigned short* __restrict__ X1, const unsigned short* __restrict__ W11,
        const float* __restrict__ b11, const unsigned short* __restrict__ W21,
        const float* __restrict__ b21, unsigned short* __restrict__ O1) {
    __shared__ unsigned short Ax[16 * 512];
    __shared__ unsigned short Wl[8192];
    int b = blockIdx.x;
    if (b < nb0) gatepair_body(X0, W10, b10, W20, b20, O0, b, Ax, Wl);
    else         gatepair_body(X1, W11, b11, W21, b21, O1, b - nb0, Ax, Wl);
}

// ---------------- CSR gather-aggregation body (prescaled y') --------------------------
// out[v] = relu(dinv[v]*(y'[v] + sum_s y'[s]) + bias)
__device__ __forceinline__ void gagg_body(const unsigned short* __restrict__ y,
                                          const int* __restrict__ ptr,
                                          const int* __restrict__ esrc,
                                          const float* __restrict__ dinv,
                                          const float* __restrict__ bias,
                                          unsigned short* __restrict__ ob,
                                          int idx, int nch, int lane) {
    int v = idx / nch, ch = idx - v * nch;
    int C = nch << 7;
    int c0 = (ch << 7) + lane * 2;
    unsigned yv = *(const unsigned*)(y + (size_t)v * C + c0);
    float a0 = bf2f((unsigned short)yv);
    float a1 = bf2f((unsigned short)(yv >> 16));
    int e = ptr[v], e1 = ptr[v + 1];
    for (; e + 3 < e1; e += 4) {
        int s0 = esrc[e], s1 = esrc[e + 1], s2 = esrc[e + 2], s3 = esrc[e + 3];
        unsigned w0 = *(const unsigned*)(y + (size_t)s0 * C + c0);
        unsigned w1 = *(const unsigned*)(y + (size_t)s1 * C + c0);
        unsigned w2 = *(const unsigned*)(y + (size_t)s2 * C + c0);
        unsigned w3 = *(const unsigned*)(y + (size_t)s3 * C + c0);
        a0 += bf2f((unsigned short)w0) + bf2f((unsigned short)w1)
            + bf2f((unsigned short)w2) + bf2f((unsigned short)w3);
        a1 += bf2f((unsigned short)(w0 >> 16)) + bf2f((unsigned short)(w1 >> 16))
            + bf2f((unsigned short)(w2 >> 16)) + bf2f((unsigned short)(w3 >> 16));
    }
    for (; e < e1; ++e) {
        int s0 = esrc[e];
        unsigned w0 = *(const unsigned*)(y + (size_t)s0 * C + c0);
        a0 += bf2f((unsigned short)w0);
        a1 += bf2f((unsigned short)(w0 >> 16));
    }
    float dv = dinv[v];
    a0 = fmaxf(dv * a0 + bias[c0], 0.f);
    a1 = fmaxf(dv * a1 + bias[c0 + 1], 0.f);
    *(unsigned*)(ob + (size_t)v * C + c0) = (unsigned)f2bf(a0) | ((unsigned)f2bf(a1) << 16);
}

// fused gagg: wave-tasks [0, N0*nch0) set 0, rest set 1
__global__ __launch_bounds__(256) void k_gagg2(
        const unsigned short* __restrict__ y0, const int* __restrict__ ptr0,
        const int* __restrict__ esrc0, const float* __restrict__ dinv0,
        const float* __restrict__ bias0, unsigned short* __restrict__ ob0, int N0, int nch0,
        const unsigned short* __restrict__ y1, const int* __restrict__ ptr1,
        const int* __restrict__ esrc1, const float* __restrict__ dinv1,
        const float* __restrict__ bias1, unsigned short* __restrict__ ob1, int N1, int nch1) {
    int idx = blockIdx.x * 4 + (threadIdx.x >> 6);
    int lane = threadIdx.x & 63;
    int T0 = N0 * nch0;
    if (idx < T0) gagg_body(y0, ptr0, esrc0, dinv0, bias0, ob0, idx, nch0, lane);
    else {
        idx -= T0;
        if (idx < N1 * nch1) gagg_body(y1, ptr1, esrc1, dinv1, bias1, ob1, idx, nch1, lane);
    }
}

// ---------------- tweet attention pooling (S=30, bf16 in, bf16 out) ----------------
__global__ __launch_bounds__(128) void k_attpool(const unsigned short* __restrict__ x,
                                                 const unsigned short* __restrict__ gate,
                                                 unsigned short* __restrict__ outb, int S) {
    int seg = blockIdx.x;
    int c = threadIdx.x;
    size_t base = (size_t)seg * S * 128 + c;
    float m = -1e30f;
    for (int n = 0; n < S; ++n) m = fmaxf(m, bf2f(gate[base + (size_t)n * 128]));
    float se = 0.f, acc = 0.f;
    for (int n = 0; n < S; ++n) {
        float g = bf2f(gate[base + (size_t)n * 128]);
        float e = expf(g - m);
        se += e;
        acc += e * bf2f(x[base + (size_t)n * 128]);
    }
    outb[(size_t)seg * 128 + c] = f2bf(acc / (se + 1e-16f));
}

// ---------------- user attention pooling: chunked 3-stage (S=625, bf16 in) -------------
__global__ __launch_bounds__(256) void k_pool_pmax(const unsigned short* __restrict__ gate,
                                                   float* __restrict__ pmax, int S) {
    int seg = blockIdx.x, ch = blockIdx.y;
    int c = threadIdx.x & 127, j = threadIdx.x >> 7;
    int csz = (S + NCHUNK - 1) / NCHUNK;
    int n0 = ch * csz, n1 = min(S, n0 + csz);
    size_t base = (size_t)seg * S * 128 + c;
    float m = -1e30f;
    for (int n = n0 + j; n < n1; n += 2)
        m = fmaxf(m, bf2f(gate[base + (size_t)n * 128]));
    __shared__ float red[2][128];
    red[j][c] = m;
    __syncthreads();
    if (j == 0)
        pmax[((size_t)seg * NCHUNK + ch) * 128 + c] = fmaxf(red[0][c], red[1][c]);
}

__global__ __launch_bounds__(256) void k_pool_psum(const unsigned short* __restrict__ x,
                                                   const unsigned short* __restrict__ gate,
                                                   const float* __restrict__ pmax,
                                                   float* __restrict__ pse,
                                                   float* __restrict__ pacc, int S) {
    int seg = blockIdx.x, ch = blockIdx.y;
    int c = threadIdx.x & 127, j = threadIdx.x >> 7;
    int csz = (S + NCHUNK - 1) / NCHUNK;
    int n0 = ch * csz, n1 = min(S, n0 + csz);
    size_t base = (size_t)seg * S * 128 + c;
    float m = -1e30f;
#pragma unroll
    for (int ch2 = 0; ch2 < NCHUNK; ++ch2)
        m = fmaxf(m, pmax[((size_t)seg * NCHUNK + ch2) * 128 + c]);
    float se = 0.f, acc = 0.f;
    for (int n = n0 + j; n < n1; n += 2) {
        float g = bf2f(gate[base + (size_t)n * 128]);
        float e = expf(g - m);
        se += e;
        acc += e * bf2f(x[base + (size_t)n * 128]);
    }
    __shared__ float rs[2][128], ra[2][128];
    rs[j][c] = se; ra[j][c] = acc;
    __syncthreads();
    if (j == 0) {
        size_t o = ((size_t)seg * NCHUNK + ch) * 128 + c;
        pse[o]  = rs[0][c] + rs[1][c];
        pacc[o] = ra[0][c] + ra[1][c];
    }
}

__global__ __launch_bounds__(128) void k_pool_final(const float* __restrict__ pse,
                                                    const float* __restrict__ pacc,
                                                    float* __restrict__ out) {
    int seg = blockIdx.x, c = threadIdx.x;
    float se = 0.f, acc = 0.f;
    for (int ch = 0; ch < NCHUNK; ++ch) {
        size_t o = ((size_t)seg * NCHUNK + ch) * 128 + c;
        se += pse[o];
        acc += pacc[o];
    }
    out[(size_t)seg * 128 + c] = acc / (se + 1e-16f);
}

// ---------------- GRU recurrence (gi fp32 precomputed): 64 blocks x 768 threads --------
__global__ __launch_bounds__(768) void k_gru_rec(const float* __restrict__ gi,
                                                 const float* __restrict__ whhT,  // [128][384]
                                                 const float* __restrict__ bhh,
                                                 float* __restrict__ hT) {
    __shared__ float hs[128];
    __shared__ float ph[768];
    int b = blockIdx.x, t = threadIdx.x;
    int half = (t >= 384) ? 1 : 0;
    int j = t - half * 384;
    float w[64];
#pragma unroll
    for (int i = 0; i < 64; ++i)
        w[i] = whhT[(half * 64 + i) * 384 + j];
    float chr = 0.f, chz = 0.f, chn = 0.f;
    if (t < 128) {
        hs[t] = 0.f;
        chr = bhh[t]; chz = bhh[128 + t]; chn = bhh[256 + t];
    }
    __syncthreads();
    for (int step = 0; step < TT; ++step) {
        float a0 = 0.f, a1 = 0.f, a2 = 0.f, a3 = 0.f;
        const float* hbase = hs + half * 64;
#pragma unroll
        for (int i = 0; i < 64; i += 4) {
            float4 hv = *(const float4*)(hbase + i);
            a0 += hv.x * w[i + 0];
            a1 += hv.y * w[i + 1];
            a2 += hv.z * w[i + 2];
            a3 += hv.w * w[i + 3];
        }
        ph[t] = (a0 + a1) + (a2 + a3);
        __syncthreads();
        float hnew = 0.f;
        if (t < 128) {
            const float* girow = gi + ((size_t)b * TT + step) * 384;
            float hr = ph[t] + ph[t + 384] + chr;
            float hz = ph[128 + t] + ph[512 + t] + chz;
            float hn = ph[256 + t] + ph[640 + t] + chn;
            float ir = girow[t], iz = girow[128 + t], in = girow[256 + t];
            float r = 1.f / (1.f + expf(-(ir + hr)));
            float z = 1.f / (1.f + expf(-(iz + hz)));
            float n = tanhf(in + r * hn);
            hnew = (1.f - z) * n + z * hs[t];
        }
        __syncthreads();
        if (t < 128) hs[t] = hnew;
        __syncthreads();
    }
    if (t < 128) hT[(size_t)b * 128 + t] = hs[t];
}

// ---------------- head MLP ----------------
__global__ __launch_bounds__(256) void k_head(const float* __restrict__ uf,
                                              const float* __restrict__ up,
                                              const float* __restrict__ th,
                                              const float* __restrict__ Wd0, const float* __restrict__ bd0,
                                              const float* __restrict__ Wd1, const float* __restrict__ bd1,
                                              const float* __restrict__ Wp, const float* __restrict__ bp,
                                              float* __restrict__ out) {
    __shared__ float in0[288], l1[256], l2[64];
    int b = blockIdx.x, t = threadIdx.x;
    if (t < 32) in0[t] = uf[b * 32 + t];
    else if (t < 160) in0[t] = up[b * 128 + (t - 32)];
    if (t < 128) in0[160 + t] = th[b * 128 + t];
    __syncthreads();
    float acc = bd0[t];
    for (int k = 0; k < 288; ++k) acc += in0[k] * Wd0[k * 256 + t];
    l1[t] = fmaxf(acc, 0.f);
    __syncthreads();
    if (t < 64) {
        float a2 = bd1[t];
        for (int k = 0; k < 256; ++k) a2 += l1[k] * Wd1[k * 64 + t];
        l2[t] = fmaxf(a2, 0.f);
    }
    __syncthreads();
    if (t < 64) {
        float p = l2[t] * Wp[t];
        for (int off = 32; off; off >>= 1) p += __shfl_down(p, off, 64);
        if (t == 0) out[b] = 1.f / (1.f + expf(-(p + bp[0])));
    }
}

// ---------------- launch ----------------
extern "C" void kernel_launch(void* const* d_in, const int* in_sizes, int n_in,
                              void* d_out, int out_size, void* d_ws, size_t ws_size,
                              hipStream_t stream) {
    const float* user_x     = (const float*)d_in[0];
    const float* user_feats = (const float*)d_in[1];
    const float* tweet_x    = (const float*)d_in[2];
    const float* Wu0 = (const float*)d_in[3];  const float* bu0 = (const float*)d_in[4];
    const float* Wu1 = (const float*)d_in[5];  const float* bu1 = (const float*)d_in[6];
    const float* Wgu1 = (const float*)d_in[7]; const float* bgu1 = (const float*)d_in[8];
    const float* Wgu2 = (const float*)d_in[9]; const float* bgu2 = (const float*)d_in[10];
    const float* Wt0 = (const float*)d_in[11]; const float* bt0 = (const float*)d_in[12];
    const float* Wt1 = (const float*)d_in[13]; const float* bt1 = (const float*)d_in[14];
    const float* Wgt1 = (const float*)d_in[15]; const float* bgt1 = (const float*)d_in[16];
    const float* Wgt2 = (const float*)d_in[17]; const float* bgt2 = (const float*)d_in[18];
    const float* W_ih = (const float*)d_in[19]; const float* b_ih = (const float*)d_in[20];
    const float* W_hh = (const float*)d_in[21]; const float* b_hh = (const float*)d_in[22];
    const float* Wd0 = (const float*)d_in[23]; const float* bd0 = (const float*)d_in[24];
    const float* Wd1 = (const float*)d_in[25]; const float* bd1 = (const float*)d_in[26];
    const float* Wp  = (const float*)d_in[27]; const float* bp  = (const float*)d_in[28];
    const int* ue = (const int*)d_in[29];
    const int* te = (const int*)d_in[30];
    const int* ue_src = ue, *ue_dst = ue + EU;
    const int* te_src = te, *te_dst = te + NTE;

    // ---- workspace layout ----
    float* ws = (float*)d_ws;
    size_t o = 0;
    float* dinv_u = ws + o;     o += NU;
    float* dinv_t = ws + o;     o += NTNODES;       // contiguous after dinv_u
    float* user_pool = ws + o;  o += (size_t)BB * 128;
    float* tweet_h = ws + o;    o += (size_t)BB * 128;
    float* whhT = ws + o;       o += 128 * 384;
    float* gi = ws + o;         o += (size_t)NSEG_T * 384;
    float* pmax = ws + o;       o += 131072;
    float* pse = ws + o;        o += 131072;
    float* pacc = ws + o;       o += 131072;
    int* iw = (int*)(ws + o);
    int* hist_u = iw;
    int* hist_t = iw + NU;
    int* ptr_u  = iw + NU + NTNODES;
    int* fill_u = ptr_u + NU + 1;
    int* esrc_u = fill_u + NU;
    int* ptr_t  = esrc_u + EU;
    int* fill_t = ptr_t + NTNODES + 1;
    int* esrc_t = fill_t + NTNODES;
    int* bsum_u = esrc_t + NTE;
    int* bsum_t = bsum_u + 256;
    unsigned short* pk = (unsigned short*)(((uintptr_t)(bsum_t + 256) + 15) & ~(uintptr_t)15);
    unsigned short* pWu0  = pk;
    unsigned short* pWu1  = pWu0  + 16384;
    unsigned short* pWgu1 = pWu1  + 16384;
    unsigned short* pWgu2 = pWgu1 + 16384;
    unsigned short* pWt0  = pWgu2 + 16384;
    unsigned short* pWt1  = pWt0  + 196608;
    unsigned short* pWgt1 = pWt1  + 32768;
    unsigned short* pWgt2 = pWgt1 + 16384;
    unsigned short* pWih  = pWgt2 + 16384;
    // bf16 arena: 4 slots of NT*256 halfwords
    unsigned short* arena = (unsigned short*)(((uintptr_t)(pWih + 49152) + 15) & ~(uintptr_t)15);
    const size_t SLOT = (size_t)NTNODES * 256;      // 7,864,320 hw
    unsigned short* P0 = arena;
    unsigned short* P1 = P0 + SLOT;
    unsigned short* P2 = P1 + SLOT;
    unsigned short* P3 = P2 + SLOT;
    unsigned short* tpool_bf = P3 + SLOT;           // 1024*128 hw
    float* out = (float*)d_out;

    dim3 b256(256);
    const float* ND = nullptr;

    // ---- packs + whh transpose ----
    hipLaunchKernelGGL(k_packall, dim3((425984 + 255) / 256), b256, 0, stream,
                       Wu0, Wu1, Wgu1, Wgu2, Wt0, Wt1, Wgt1, Wgt2, W_ih, W_hh, whhT, pk);

    // ---- degrees + CSR (fused user+tweet) ----
    hipLaunchKernelGGL(k_zeroint, dim3((NU + NTNODES + 255) / 256), b256, 0, stream,
                       hist_u, NU + NTNODES);
    hipLaunchKernelGGL(k_hist2, dim3((EU + NTE + 255) / 256), b256, 0, stream,
                       ue_dst, te_dst, hist_u, hist_t);
    hipLaunchKernelGGL(k_scan_a2, dim3(NBU + NBT), b256, 0, stream, hist_u, bsum_u, bsum_t);
    hipLaunchKernelGGL(k_scan_b2, dim3(2), b256, 0, stream, bsum_u, bsum_t);
    hipLaunchKernelGGL(k_scan_c2, dim3(NBU + NBT), b256, 0, stream,
                       hist_u, bsum_u, bsum_t, ptr_u, fill_u, ptr_t, fill_t, dinv_u);
    hipLaunchKernelGGL(k_place2, dim3((EU + NTE + 255) / 256), b256, 0, stream,
                       ue_src, ue_dst, te_src, te_dst, fill_u, esrc_u, fill_t, esrc_t);

    // ---- J1: tweet conv1 (fp32 A, bn 0-1 -> P0) + user gemm1 (fp32 A, bn 2 -> P2) ----
    hipLaunchKernelGGL(HIP_KERNEL_NAME(k_mgemm_dual<true>), dim3(NU / 32, 3), b256, 0, stream,
                       (const void*)tweet_x, pWt0, dinv_t, (void*)P0, NTNODES, 768, 256,
                       (const void*)user_x,  pWu0, dinv_u, (void*)P2, NU,      128, 128,
                       2);
    // ---- J2: tweet gagg1 (P0 -> h1t@P1) + user gagg1 (P2 -> h1u@P3) ----
    hipLaunchKernelGGL(k_gagg2, dim3((NTNODES * 2 + NU + 3) / 4), b256, 0, stream,
                       P0, ptr_t, esrc_t, dinv_t, bt0, P1, NTNODES, 2,
                       P2, ptr_u, esrc_u, dinv_u, bu0, P3, NU, 1);
    // ---- J3: tweet gemm2 (h1t@P1 -> y2t'@P2) + user gemm2 (h1u@P3 -> y2u'@P0) ----
    hipLaunchKernelGGL(HIP_KERNEL_NAME(k_mgemm_dual<false>), dim3(NU / 32, 2), b256, 0, stream,
                       (const void*)P1, pWt1, dinv_t, (void*)P2, NTNODES, 256, 128,
                       (const void*)P3, pWu1, dinv_u, (void*)P0, NU,      128, 128,
                       1);
    // ---- J4: tweet gagg2 (P2 -> g2t@P1) + user gagg2 (P0 -> h2u@P3) ----
    hipLaunchKernelGGL(k_gagg2, dim3((NTNODES + NU + 3) / 4), b256, 0, stream,
                       P2, ptr_t, esrc_t, dinv_t, bt1, P1, NTNODES, 1,
                       P0, ptr_u, esrc_u, dinv_u, bu1, P3, NU, 1);
    // ---- J5: user gatepair (h2u@P3 -> gate_u@P0) + tweet gatepair (g2t@P1 -> gate_t@P2) ----
    hipLaunchKernelGGL(k_gatepair2, dim3(NU / 64 + NTNODES / 64), b256, 0, stream,
                       P3, pWgu1, bgu1, pWgu2, bgu2, P0, NU / 64,
                       P1, pWgt1, bgt1, pWgt2, bgt2, P2);

    // ---- pools ----
    hipLaunchKernelGGL(k_pool_pmax, dim3(BB, NCHUNK), b256, 0, stream, P0, pmax, NU / BB);
    hipLaunchKernelGGL(k_pool_psum, dim3(BB, NCHUNK), b256, 0, stream,
                       P3, P0, pmax, pse, pacc, NU / BB);
    hipLaunchKernelGGL(k_pool_final, dim3(BB), dim3(128), 0, stream, pse, pacc, user_pool);
    hipLaunchKernelGGL(k_attpool, dim3(NSEG_T), dim3(128), 0, stream,
                       P1, P2, tpool_bf, NW);

    // ---- GRU: gi = tweet_pool @ W_ih^T + b_ih (fp32 out) ----
    hipLaunchKernelGGL(HIP_KERNEL_NAME(k_mgemm<false>), dim3(NSEG_T / 32, 3), b256, 0, stream,
                       (const void*)tpool_bf, pWih, b_ih, ND, (void*)gi, NSEG_T, 128, 384, 5);
    hipLaunchKernelGGL(k_gru_rec, dim3(BB), dim3(768), 0, stream,
                       gi, whhT, b_hh, tweet_h);

    // ---- head ----
    hipLaunchKernelGGL(k_head, dim3(BB), b256, 0, stream,
                       user_feats, user_pool, tweet_h,
                       Wd0, bd0, Wd1, bd1, Wp, bp, out);
}

// Round 16
// 323.576 us; speedup vs baseline: 1.2795x; 1.0123x over previous
//
#include <hip/hip_runtime.h>
#include <hip/hip_bf16.h>

// ---------------- problem constants ----------------
#define NU 40000
#define EU 640000
#define BB 64
#define TT 16
#define NW 30
#define NTNODES 30720       // B*T*NW
#define NTE 61440           // tweet edges
#define NSEG_T 1024         // B*T
#define NCHUNK 16           // chunks per user segment for att-pool
#define NBU 157             // ceil(NU/256)
#define NBT 120             // NTNODES/256

typedef __attribute__((ext_vector_type(8))) short bf16x8;
typedef __attribute__((ext_vector_type(4))) float f32x4;

__device__ __forceinline__ unsigned short f2bf(float x) {
    union { float f; unsigned u; } v; v.f = x;
    unsigned r = v.u + 0x7FFFu + ((v.u >> 16) & 1u);   // RNE
    return (unsigned short)(r >> 16);
}
__device__ __forceinline__ float bf2f(unsigned short u) {
    union { unsigned u; float f; } v; v.u = (unsigned)u << 16; return v.f;
}
// async 16B global->LDS (per-lane global src; LDS dest = wave-uniform base + lane*16)
__device__ __forceinline__ void gld16(const unsigned short* g, unsigned short* l) {
    __builtin_amdgcn_global_load_lds(
        (const __attribute__((address_space(1))) void*)g,
        (__attribute__((address_space(3))) void*)l, 16, 0, 0);
}

// ---------------- degree / CSR build (fused user+tweet) ----------------
__global__ void k_zeroint(int* __restrict__ p, int n) {
    int i = blockIdx.x * blockDim.x + threadIdx.x;
    if (i < n) p[i] = 0;
}

__global__ void k_hist2(const int* __restrict__ ue_dst, const int* __restrict__ te_dst,
                        int* __restrict__ hist_u, int* __restrict__ hist_t) {
    int i = blockIdx.x * blockDim.x + threadIdx.x;
    if (i < EU) atomicAdd(&hist_u[ue_dst[i]], 1);
    else if (i < EU + NTE) atomicAdd(&hist_t[te_dst[i - EU]], 1);
}

__global__ __launch_bounds__(256) void k_scan_a2(const int* __restrict__ hist_u,
                                                 int* __restrict__ bsum_u,
                                                 int* __restrict__ bsum_t) {
    __shared__ int red[256];
    int b = blockIdx.x, t = threadIdx.x;
    const int* h; int* bs; int n, lb;
    if (b < NBU) { h = hist_u;      bs = bsum_u; n = NU;      lb = b; }
    else         { h = hist_u + NU; bs = bsum_t; n = NTNODES; lb = b - NBU; }
    int i = lb * 256 + t;
    red[t] = (i < n) ? h[i] : 0;
    __syncthreads();
    for (int off = 128; off; off >>= 1) {
        if (t < off) red[t] += red[t + off];
        __syncthreads();
    }
    if (t == 0) bs[lb] = red[0];
}

__global__ __launch_bounds__(256) void k_scan_b2(int* __restrict__ bsum_u,
                                                 int* __restrict__ bsum_t) {
    __shared__ int s[256];
    int t = threadIdx.x;
    int* bs = blockIdx.x ? bsum_t : bsum_u;
    int nb  = blockIdx.x ? NBT : NBU;
    s[t] = (t < nb) ? bs[t] : 0;
    __syncthreads();
    for (int off = 1; off < 256; off <<= 1) {
        int v = (t >= off) ? s[t - off] : 0;
        __syncthreads();
        s[t] += v;
        __syncthreads();
    }
    if (t < nb) bs[t] = (t == 0) ? 0 : s[t - 1];
}

__global__ __launch_bounds__(256) void k_scan_c2(const int* __restrict__ hist_u,
                                                 const int* __restrict__ bsum_u,
                                                 const int* __restrict__ bsum_t,
                                                 int* __restrict__ ptr_u, int* __restrict__ fill_u,
                                                 int* __restrict__ ptr_t, int* __restrict__ fill_t,
                                                 float* __restrict__ dinv_u) {
    __shared__ int s[256];
    int b = blockIdx.x, t = threadIdx.x;
    const int *h, *bs; int *ptr, *fill; int n, lb; float* dv;
    if (b < NBU) { h = hist_u;      bs = bsum_u; ptr = ptr_u; fill = fill_u; n = NU;      lb = b;       dv = dinv_u; }
    else         { h = hist_u + NU; bs = bsum_t; ptr = ptr_t; fill = fill_t; n = NTNODES; lb = b - NBU; dv = dinv_u + NU; }
    int i = lb * 256 + t;
    int hv = (i < n) ? h[i] : 0;
    s[t] = hv;
    __syncthreads();
    for (int off = 1; off < 256; off <<= 1) {
        int v = (t >= off) ? s[t - off] : 0;
        __syncthreads();
        s[t] += v;
        __syncthreads();
    }
    if (i < n) {
        int excl = bs[lb] + s[t] - hv;
        ptr[i] = excl;
        fill[i] = excl;
        dv[i] = rsqrtf((float)hv + 1.0f);
        if (i == n - 1) ptr[n] = excl + hv;
    }
}

__global__ void k_place2(const int* __restrict__ ue_src, const int* __restrict__ ue_dst,
                         const int* __restrict__ te_src, const int* __restrict__ te_dst,
                         int* __restrict__ fill_u, int* __restrict__ esrc_u,
                         int* __restrict__ fill_t, int* __restrict__ esrc_t) {
    int e = blockIdx.x * blockDim.x + threadIdx.x;
    if (e < EU) {
        int pos = atomicAdd(&fill_u[ue_dst[e]], 1);
        esrc_u[pos] = ue_src[e];
    } else if (e < EU + NTE) {
        int e2 = e - EU;
        int pos = atomicAdd(&fill_t[te_dst[e2]], 1);
        esrc_t[pos] = te_src[e2];
    }
}

// ---------------- weight pre-pack (9 weights + W_hh transpose, one kernel) ------------
__device__ __forceinline__ void pack_one(const float* __restrict__ W,
                                         unsigned short* __restrict__ out,
                                         int f, int K, int N, int trans) {
    int j = f & 7;
    int chunk = f >> 3;
    int c = chunk & 511;
    int panel = chunk >> 9;
    int KS = K >> 5;
    int ks = panel % KS;
    int bn = panel / KS;
    int n = bn * 128 + (c & 127);
    int k = ks * 32 + (c >> 7) * 8 + j;
    float v = trans ? W[(size_t)n * K + k] : W[(size_t)k * N + n];
    out[f] = f2bf(v);
}

__global__ void k_packall(const float* __restrict__ Wu0, const float* __restrict__ Wu1,
                          const float* __restrict__ Wgu1, const float* __restrict__ Wgu2,
                          const float* __restrict__ Wt0, const float* __restrict__ Wt1,
                          const float* __restrict__ Wgt1, const float* __restrict__ Wgt2,
                          const float* __restrict__ Wih,
                          const float* __restrict__ Whh, float* __restrict__ whhT,
                          unsigned short* __restrict__ pk) {
    int f = blockIdx.x * blockDim.x + threadIdx.x;
    if (f < 16384)        pack_one(Wu0,  pk + 0,      f,          128, 128, 0);
    else if (f < 32768)   pack_one(Wu1,  pk + 16384,  f - 16384,  128, 128, 0);
    else if (f < 49152)   pack_one(Wgu1, pk + 32768,  f - 32768,  128, 128, 0);
    else if (f < 65536)   pack_one(Wgu2, pk + 49152,  f - 49152,  128, 128, 0);
    else if (f < 262144)  pack_one(Wt0,  pk + 65536,  f - 65536,  768, 256, 0);
    else if (f < 294912)  pack_one(Wt1,  pk + 262144, f - 262144, 256, 128, 0);
    else if (f < 311296)  pack_one(Wgt1, pk + 294912, f - 294912, 128, 128, 0);
    else if (f < 327680)  pack_one(Wgt2, pk + 311296, f - 311296, 128, 128, 0);
    else if (f < 376832)  pack_one(Wih,  pk + 327680, f - 327680, 128, 384, 1);
    else if (f < 425984) {                          // W_hh [384][128] -> whhT [128][384]
        int j2 = f - 376832;
        int r = j2 >> 7, k2 = j2 & 127;
        whhT[k2 * 384 + r] = Whh[j2];
    }
}

// ---------------- bf16 MFMA GEMM body, BM=32 BN=NPAN*128 BK=64 ----------------
// AF32: A fp32 (reg-staged+convert, padded planes). !AF32: A bf16 (global_load_lds).
// NPAN: N-panels per block (A staged once, reused across panels).
// flags: 1=bias, 2=relu, 4=fp32 out. dscale: if non-null, C row scaled (pre-bias).
// M%32==0, K%64==0, N%(NPAN*128)==0.
template<bool AF32, int NPAN>
__device__ __forceinline__ void mgemm_body(const void* __restrict__ Araw,
                                           const unsigned short* __restrict__ Bpk,
                                           const float* __restrict__ bias,
                                           const float* __restrict__ dscale,
                                           void* __restrict__ Craw,
                                           int M, int K, int N, int flags,
                                           int bm, int bnBase,
                                           unsigned short* Alds, unsigned short* Blds) {
    constexpr int AST = AF32 ? 260 : 256;
    int tid = threadIdx.x, lane = tid & 63, w = tid >> 6;
    int wr = (w >> 1) * 16, wc = (w & 1) * 64;
    int l15 = lane & 15, lk = lane >> 4;

    f32x4 acc[NPAN][4];
#pragma unroll
    for (int p = 0; p < NPAN; ++p)
#pragma unroll
        for (int n = 0; n < 4; ++n) acc[p][n] = (f32x4){0.f, 0.f, 0.f, 0.f};

    int KS32 = K >> 5;
    const unsigned short* Bpan[NPAN];
#pragma unroll
    for (int p = 0; p < NPAN; ++p)
        Bpan[p] = Bpk + (size_t)(bnBase * NPAN + p) * KS32 * 4096;
    int KS64 = K >> 6;

    for (int ks = 0; ks < KS64; ++ks) {
        int k0 = ks * 64;
        // ---- stage B: NPAN panels x 8192 hw via global_load_lds ----
#pragma unroll
        for (int p = 0; p < NPAN; ++p) {
            const unsigned short* bg = Bpan[p] + (size_t)ks * 8192;
#pragma unroll
            for (int q = 0; q < 4; ++q) {
                int off = (w * 4 + q) * 512;
                gld16(bg + off + lane * 8, &Blds[p * 8192 + off]);
            }
        }
        // ---- stage A (32 rows x 64 k), shared across panels ----
        if (AF32) {
            const float* A = (const float*)Araw;
#pragma unroll
            for (int p = 0; p < 2; ++p) {
                int f4 = p * 256 + tid;
                int row = f4 >> 4;
                int kq  = f4 & 15;
                float4 av = *(const float4*)(A + (size_t)(bm * 32 + row) * K + k0 + kq * 4);
                unsigned lo = (unsigned)f2bf(av.x) | ((unsigned)f2bf(av.y) << 16);
                unsigned hi = (unsigned)f2bf(av.z) | ((unsigned)f2bf(av.w) << 16);
                int off = (kq >> 1) * AST + row * 8 + (kq & 1) * 4;
                *(uint2*)&Alds[off] = make_uint2(lo, hi);
            }
        } else {
            const unsigned short* A = (const unsigned short*)Araw;
            int kblk = 2 * w + (lane >> 5);
            int row = lane & 31;
            gld16(A + (size_t)(bm * 32 + row) * K + k0 + kblk * 8,
                  &Alds[w * 512]);
        }
        __syncthreads();
#pragma unroll
        for (int h = 0; h < 2; ++h) {
            int kb = h * 4 + lk;
            bf16x8 a = *(const bf16x8*)&Alds[kb * AST + (wr + l15) * 8];
#pragma unroll
            for (int p = 0; p < NPAN; ++p) {
                bf16x8 b[4];
#pragma unroll
                for (int n = 0; n < 4; ++n)
                    b[n] = *(const bf16x8*)&Blds[p * 8192 + kb * 1024 + (wc + n * 16 + l15) * 8];
#pragma unroll
                for (int n = 0; n < 4; ++n)
                    acc[p][n] = __builtin_amdgcn_mfma_f32_16x16x32_bf16(a, b[n], acc[p][n], 0, 0, 0);
            }
        }
        __syncthreads();
    }

    int grow0 = bm * 32 + wr + lk * 4;
#pragma unroll
    for (int i = 0; i < 4; ++i) {
        int grow = grow0 + i;
        float ds = dscale ? dscale[grow] : 1.f;
#pragma unroll
        for (int p = 0; p < NPAN; ++p)
#pragma unroll
            for (int n = 0; n < 4; ++n) {
                int gcol = (bnBase * NPAN + p) * 128 + wc + n * 16 + l15;
                float v = acc[p][n][i] * ds;
                if (flags & 1) v += bias[gcol];
                if (flags & 2) v = fmaxf(v, 0.f);
                if (flags & 4) ((float*)Craw)[(size_t)grow * N + gcol] = v;
                else ((unsigned short*)Craw)[(size_t)grow * N + gcol] = f2bf(v);
            }
    }
}

template<bool AF32>
__global__ __launch_bounds__(256) void k_mgemm(const void* __restrict__ Araw,
                                               const unsigned short* __restrict__ Bpk,
                                               const float* __restrict__ bias,
                                               const float* __restrict__ dscale,
                                               void* __restrict__ Craw,
                                               int M, int K, int N, int flags) {
    constexpr int AST = AF32 ? 260 : 256;
    __shared__ unsigned short Alds[8 * AST];
    __shared__ unsigned short Blds[8192];
    if (blockIdx.x * 32 >= M) return;
    mgemm_body<AF32, 1>(Araw, Bpk, bias, dscale, Craw, M, K, N, flags,
                        blockIdx.x, blockIdx.y, Alds, Blds);
}

// dual GEMM: grid.y in [0,bnSplit) -> set 0 (NP0 panels), [bnSplit,..) -> set 1 (NP1)
template<bool AF32, int NP0, int NP1>
__global__ __launch_bounds__(256) void k_mgemm_dual(
        const void* __restrict__ A0, const unsigned short* __restrict__ B0,
        const float* __restrict__ ds0, void* __restrict__ C0, int M0, int K0, int N0,
        const void* __restrict__ A1, const unsigned short* __restrict__ B1,
        const float* __restrict__ ds1, void* __restrict__ C1, int M1, int K1, int N1,
        int bnSplit) {
    constexpr int AST = AF32 ? 260 : 256;
    constexpr int NPmax = NP0 > NP1 ? NP0 : NP1;
    __shared__ unsigned short Alds[8 * AST];
    __shared__ unsigned short Blds[NPmax * 8192];
    int bn = blockIdx.y, bm = blockIdx.x;
    if (bn < bnSplit) {
        if (bm * 32 >= M0) return;
        mgemm_body<AF32, NP0>(A0, B0, (const float*)nullptr, ds0, C0, M0, K0, N0, 0,
                              bm, bn, Alds, Blds);
    } else {
        if (bm * 32 >= M1) return;
        mgemm_body<AF32, NP1>(A1, B1, (const float*)nullptr, ds1, C1, M1, K1, N1, 0,
                              bm, bn - bnSplit, Alds, Blds);
    }
}

// ---------------- fused gate pair body: out = (X@W1+b1)@W2+b2, K=N=128 ---------------
__device__ __forceinline__ void gatepair_body(const unsigned short* __restrict__ X,
                                              const unsigned short* __restrict__ W1,
                                              const float* __restrict__ b1,
                                              const unsigned short* __restrict__ W2,
                                              const float* __restrict__ b2,
                                              unsigned short* __restrict__ outp,
                                              int bm,
                                              unsigned short* Ax, unsigned short* Wl) {
    int tid = threadIdx.x, lane = tid & 63, w = tid >> 6;
    int wr = (w >> 1) * 32, wc = (w & 1) * 64;
    int l15 = lane & 15, lk = lane >> 4;

#pragma unroll
    for (int q = 0; q < 4; ++q) {
        int pl = w * 4 + q;
        gld16(X + (size_t)(bm * 64 + lane) * 128 + pl * 8, &Ax[pl * 512]);
    }

    f32x4 acc[2][4];
#pragma unroll
    for (int m = 0; m < 2; ++m)
#pragma unroll
        for (int n = 0; n < 4; ++n) acc[m][n] = (f32x4){0.f, 0.f, 0.f, 0.f};

    for (int ks = 0; ks < 2; ++ks) {
        const unsigned short* wp = W1 + ks * 8192;
#pragma unroll
        for (int q = 0; q < 4; ++q) {
            int off = (w * 4 + q) * 512;
            gld16(wp + off + lane * 8, &Wl[off]);
        }
        __syncthreads();
#pragma unroll
        for (int h = 0; h < 2; ++h) {
            int kb = h * 4 + lk;
            bf16x8 a[2], b[4];
#pragma unroll
            for (int m = 0; m < 2; ++m)
                a[m] = *(const bf16x8*)&Ax[(ks * 8 + kb) * 512 + (wr + m * 16 + l15) * 8];
#pragma unroll
            for (int n = 0; n < 4; ++n)
                b[n] = *(const bf16x8*)&Wl[kb * 1024 + (wc + n * 16 + l15) * 8];
#pragma unroll
            for (int m = 0; m < 2; ++m)
#pragma unroll
                for (int n = 0; n < 4; ++n)
                    acc[m][n] = __builtin_amdgcn_mfma_f32_16x16x32_bf16(a[m], b[n], acc[m][n], 0, 0, 0);
        }
        __syncthreads();
    }

#pragma unroll
    for (int m = 0; m < 2; ++m)
#pragma unroll
        for (int n = 0; n < 4; ++n) {
            int col = wc + n * 16 + l15;
            float bv = b1[col];
#pragma unroll
            for (int i = 0; i < 4; ++i) {
                int row = wr + m * 16 + lk * 4 + i;
                float v = acc[m][n][i] + bv;     // NO relu (Linear->Linear)
                Ax[(col >> 3) * 512 + row * 8 + (col & 7)] = f2bf(v);
            }
        }
    __syncthreads();

#pragma unroll
    for (int m = 0; m < 2; ++m)
#pragma unroll
        for (int n = 0; n < 4; ++n) acc[m][n] = (f32x4){0.f, 0.f, 0.f, 0.f};
    for (int ks = 0; ks < 2; ++ks) {
        const unsigned short* wp = W2 + ks * 8192;
#pragma unroll
        for (int q = 0; q < 4; ++q) {
            int off = (w * 4 + q) * 512;
            gld16(wp + off + lane * 8, &Wl[off]);
        }
        __syncthreads();
#pragma unroll
        for (int h = 0; h < 2; ++h) {
            int kb = h * 4 + lk;
            bf16x8 a[2], b[4];
#pragma unroll
            for (int m = 0; m < 2; ++m)
                a[m] = *(const bf16x8*)&Ax[(ks * 8 + kb) * 512 + (wr + m * 16 + l15) * 8];
#pragma unroll
            for (int n = 0; n < 4; ++n)
                b[n] = *(const bf16x8*)&Wl[kb * 1024 + (wc + n * 16 + l15) * 8];
#pragma unroll
            for (int m = 0; m < 2; ++m)
#pragma unroll
                for (int n = 0; n < 4; ++n)
                    acc[m][n] = __builtin_amdgcn_mfma_f32_16x16x32_bf16(a[m], b[n], acc[m][n], 0, 0, 0);
        }
        __syncthreads();
    }

#pragma unroll
    for (int m = 0; m < 2; ++m)
#pragma unroll
        for (int n = 0; n < 4; ++n) {
            int col = wc + n * 16 + l15;
            float bv = b2[col];
#pragma unroll
            for (int i = 0; i < 4; ++i) {
                int row = bm * 64 + wr + m * 16 + lk * 4 + i;
                float v = acc[m][n][i] + bv;     // NO relu
                outp[(size_t)row * 128 + col] = f2bf(v);
            }
        }
}

// fused: blocks [0,nb0) set 0, [nb0, ...) set 1
__global__ __launch_bounds__(256) void k_gatepair2(
        const unsigned short* __restrict__ X0, const unsigned short* __restrict__ W10,
        const float* __restrict__ b10, const unsigned short* __restrict__ W20,
        const float* __restrict__ b20, unsigned short* __restrict__ O0, int nb0,
        const unsigned short* __restrict__ X1, const unsigned short* __restrict__ W11,
        const float* __restrict__ b11, const unsigned short* __restrict__ W21,
        const float* __restrict__ b21, unsigned short* __restrict__ O1) {
    __shared__ unsigned short Ax[16 * 512];
    __shared__ unsigned short Wl[8192];
    int b = blockIdx.x;
    if (b < nb0) gatepair_body(X0, W10, b10, W20, b20, O0, b, Ax, Wl);
    else         gatepair_body(X1, W11, b11, W21, b21, O1, b - nb0, Ax, Wl);
}

// ---------------- CSR gather-aggregation body (prescaled y') --------------------------
// out[v] = relu(dinv[v]*(y'[v] + sum_s y'[s]) + bias)
__device__ __forceinline__ void gagg_body(const unsigned short* __restrict__ y,
                                          const int* __restrict__ ptr,
                                          const int* __restrict__ esrc,
                                          const float* __restrict__ dinv,
                                          const float* __restrict__ bias,
                                          unsigned short* __restrict__ ob,
                                          int idx, int nch, int lane) {
    int v = idx / nch, ch = idx - v * nch;
    int C = nch << 7;
    int c0 = (ch << 7) + lane * 2;
    unsigned yv = *(const unsigned*)(y + (size_t)v * C + c0);
    float a0 = bf2f((unsigned short)yv);
    float a1 = bf2f((unsigned short)(yv >> 16));
    int e = ptr[v], e1 = ptr[v + 1];
    for (; e + 3 < e1; e += 4) {
        int s0 = esrc[e], s1 = esrc[e + 1], s2 = esrc[e + 2], s3 = esrc[e + 3];
        unsigned w0 = *(const unsigned*)(y + (size_t)s0 * C + c0);
        unsigned w1 = *(const unsigned*)(y + (size_t)s1 * C + c0);
        unsigned w2 = *(const unsigned*)(y + (size_t)s2 * C + c0);
        unsigned w3 = *(const unsigned*)(y + (size_t)s3 * C + c0);
        a0 += bf2f((unsigned short)w0) + bf2f((unsigned short)w1)
            + bf2f((unsigned short)w2) + bf2f((unsigned short)w3);
        a1 += bf2f((unsigned short)(w0 >> 16)) + bf2f((unsigned short)(w1 >> 16))
            + bf2f((unsigned short)(w2 >> 16)) + bf2f((unsigned short)(w3 >> 16));
    }
    for (; e < e1; ++e) {
        int s0 = esrc[e];
        unsigned w0 = *(const unsigned*)(y + (size_t)s0 * C + c0);
        a0 += bf2f((unsigned short)w0);
        a1 += bf2f((unsigned short)(w0 >> 16));
    }
    float dv = dinv[v];
    a0 = fmaxf(dv * a0 + bias[c0], 0.f);
    a1 = fmaxf(dv * a1 + bias[c0 + 1], 0.f);
    *(unsigned*)(ob + (size_t)v * C + c0) = (unsigned)f2bf(a0) | ((unsigned)f2bf(a1) << 16);
}

// fused gagg: wave-tasks [0, N0*nch0) set 0, rest set 1
__global__ __launch_bounds__(256) void k_gagg2(
        const unsigned short* __restrict__ y0, const int* __restrict__ ptr0,
        const int* __restrict__ esrc0, const float* __restrict__ dinv0,
        const float* __restrict__ bias0, unsigned short* __restrict__ ob0, int N0, int nch0,
        const unsigned short* __restrict__ y1, const int* __restrict__ ptr1,
        const int* __restrict__ esrc1, const float* __restrict__ dinv1,
        const float* __restrict__ bias1, unsigned short* __restrict__ ob1, int N1, int nch1) {
    int idx = blockIdx.x * 4 + (threadIdx.x >> 6);
    int lane = threadIdx.x & 63;
    int T0 = N0 * nch0;
    if (idx < T0) gagg_body(y0, ptr0, esrc0, dinv0, bias0, ob0, idx, nch0, lane);
    else {
        idx -= T0;
        if (idx < N1 * nch1) gagg_body(y1, ptr1, esrc1, dinv1, bias1, ob1, idx, nch1, lane);
    }
}

// ---------------- tweet attention pooling (S=30, bf16 in, bf16 out) ----------------
__global__ __launch_bounds__(128) void k_attpool(const unsigned short* __restrict__ x,
                                                 const unsigned short* __restrict__ gate,
                                                 unsigned short* __restrict__ outb, int S) {
    int seg = blockIdx.x;
    int c = threadIdx.x;
    size_t base = (size_t)seg * S * 128 + c;
    float m = -1e30f;
    for (int n = 0; n < S; ++n) m = fmaxf(m, bf2f(gate[base + (size_t)n * 128]));
    float se = 0.f, acc = 0.f;
    for (int n = 0; n < S; ++n) {
        float g = bf2f(gate[base + (size_t)n * 128]);
        float e = expf(g - m);
        se += e;
        acc += e * bf2f(x[base + (size_t)n * 128]);
    }
    outb[(size_t)seg * 128 + c] = f2bf(acc / (se + 1e-16f));
}

// ---------------- user attention pooling: chunked 3-stage (S=625, bf16 in) -------------
__global__ __launch_bounds__(256) void k_pool_pmax(const unsigned short* __restrict__ gate,
                                                   float* __restrict__ pmax, int S) {
    int seg = blockIdx.x, ch = blockIdx.y;
    int c = threadIdx.x & 127, j = threadIdx.x >> 7;
    int csz = (S + NCHUNK - 1) / NCHUNK;
    int n0 = ch * csz, n1 = min(S, n0 + csz);
    size_t base = (size_t)seg * S * 128 + c;
    float m = -1e30f;
    for (int n = n0 + j; n < n1; n += 2)
        m = fmaxf(m, bf2f(gate[base + (size_t)n * 128]));
    __shared__ float red[2][128];
    red[j][c] = m;
    __syncthreads();
    if (j == 0)
        pmax[((size_t)seg * NCHUNK + ch) * 128 + c] = fmaxf(red[0][c], red[1][c]);
}

__global__ __launch_bounds__(256) void k_pool_psum(const unsigned short* __restrict__ x,
                                                   const unsigned short* __restrict__ gate,
                                                   const float* __restrict__ pmax,
                                                   float* __restrict__ pse,
                                                   float* __restrict__ pacc, int S) {
    int seg = blockIdx.x, ch = blockIdx.y;
    int c = threadIdx.x & 127, j = threadIdx.x >> 7;
    int csz = (S + NCHUNK - 1) / NCHUNK;
    int n0 = ch * csz, n1 = min(S, n0 + csz);
    size_t base = (size_t)seg * S * 128 + c;
    float m = -1e30f;
#pragma unroll
    for (int ch2 = 0; ch2 < NCHUNK; ++ch2)
        m = fmaxf(m, pmax[((size_t)seg * NCHUNK + ch2) * 128 + c]);
    float se = 0.f, acc = 0.f;
    for (int n = n0 + j; n < n1; n += 2) {
        float g = bf2f(gate[base + (size_t)n * 128]);
        float e = expf(g - m);
        se += e;
        acc += e * bf2f(x[base + (size_t)n * 128]);
    }
    __shared__ float rs[2][128], ra[2][128];
    rs[j][c] = se; ra[j][c] = acc;
    __syncthreads();
    if (j == 0) {
        size_t o = ((size_t)seg * NCHUNK + ch) * 128 + c;
        pse[o]  = rs[0][c] + rs[1][c];
        pacc[o] = ra[0][c] + ra[1][c];
    }
}

__global__ __launch_bounds__(128) void k_pool_final(const float* __restrict__ pse,
                                                    const float* __restrict__ pacc,
                                                    float* __restrict__ out) {
    int seg = blockIdx.x, c = threadIdx.x;
    float se = 0.f, acc = 0.f;
    for (int ch = 0; ch < NCHUNK; ++ch) {
        size_t o = ((size_t)seg * NCHUNK + ch) * 128 + c;
        se += pse[o];
        acc += pacc[o];
    }
    out[(size_t)seg * 128 + c] = acc / (se + 1e-16f);
}

// ---------------- GRU recurrence (gi fp32 precomputed): 64 blocks x 768 threads --------
__global__ __launch_bounds__(768) void k_gru_rec(const float* __restrict__ gi,
                                                 const float* __restrict__ whhT,  // [128][384]
                                                 const float* __restrict__ bhh,
                                                 float* __restrict__ hT) {
    __shared__ float hs[128];
    __shared__ float ph[768];
    int b = blockIdx.x, t = threadIdx.x;
    int half = (t >= 384) ? 1 : 0;
    int j = t - half * 384;
    float w[64];
#pragma unroll
    for (int i = 0; i < 64; ++i)
        w[i] = whhT[(half * 64 + i) * 384 + j];
    float chr = 0.f, chz = 0.f, chn = 0.f;
    if (t < 128) {
        hs[t] = 0.f;
        chr = bhh[t]; chz = bhh[128 + t]; chn = bhh[256 + t];
    }
    __syncthreads();
    for (int step = 0; step < TT; ++step) {
        float a0 = 0.f, a1 = 0.f, a2 = 0.f, a3 = 0.f;
        const float* hbase = hs + half * 64;
#pragma unroll
        for (int i = 0; i < 64; i += 4) {
            float4 hv = *(const float4*)(hbase + i);
            a0 += hv.x * w[i + 0];
            a1 += hv.y * w[i + 1];
            a2 += hv.z * w[i + 2];
            a3 += hv.w * w[i + 3];
        }
        ph[t] = (a0 + a1) + (a2 + a3);
        __syncthreads();
        float hnew = 0.f;
        if (t < 128) {
            const float* girow = gi + ((size_t)b * TT + step) * 384;
            float hr = ph[t] + ph[t + 384] + chr;
            float hz = ph[128 + t] + ph[512 + t] + chz;
            float hn = ph[256 + t] + ph[640 + t] + chn;
            float ir = girow[t], iz = girow[128 + t], in = girow[256 + t];
            float r = 1.f / (1.f + expf(-(ir + hr)));
            float z = 1.f / (1.f + expf(-(iz + hz)));
            float n = tanhf(in + r * hn);
            hnew = (1.f - z) * n + z * hs[t];
        }
        __syncthreads();
        if (t < 128) hs[t] = hnew;
        __syncthreads();
    }
    if (t < 128) hT[(size_t)b * 128 + t] = hs[t];
}

// ---------------- head MLP ----------------
__global__ __launch_bounds__(256) void k_head(const float* __restrict__ uf,
                                              const float* __restrict__ up,
                                              const float* __restrict__ th,
                                              const float* __restrict__ Wd0, const float* __restrict__ bd0,
                                              const float* __restrict__ Wd1, const float* __restrict__ bd1,
                                              const float* __restrict__ Wp, const float* __restrict__ bp,
                                              float* __restrict__ out) {
    __shared__ float in0[288], l1[256], l2[64];
    int b = blockIdx.x, t = threadIdx.x;
    if (t < 32) in0[t] = uf[b * 32 + t];
    else if (t < 160) in0[t] = up[b * 128 + (t - 32)];
    if (t < 128) in0[160 + t] = th[b * 128 + t];
    __syncthreads();
    float acc = bd0[t];
    for (int k = 0; k < 288; ++k) acc += in0[k] * Wd0[k * 256 + t];
    l1[t] = fmaxf(acc, 0.f);
    __syncthreads();
    if (t < 64) {
        float a2 = bd1[t];
        for (int k = 0; k < 256; ++k) a2 += l1[k] * Wd1[k * 64 + t];
        l2[t] = fmaxf(a2, 0.f);
    }
    __syncthreads();
    if (t < 64) {
        float p = l2[t] * Wp[t];
        for (int off = 32; off; off >>= 1) p += __shfl_down(p, off, 64);
        if (t == 0) out[b] = 1.f / (1.f + expf(-(p + bp[0])));
    }
}

// ---------------- launch ----------------
extern "C" void kernel_launch(void* const* d_in, const int* in_sizes, int n_in,
                              void* d_out, int out_size, void* d_ws, size_t ws_size,
                              hipStream_t stream) {
    const float* user_x     = (const float*)d_in[0];
    const float* user_feats = (const float*)d_in[1];
    const float* tweet_x    = (const float*)d_in[2];
    const float* Wu0 = (const float*)d_in[3];  const float* bu0 = (const float*)d_in[4];
    const float* Wu1 = (const float*)d_in[5];  const float* bu1 = (const float*)d_in[6];
    const float* Wgu1 = (const float*)d_in[7]; const float* bgu1 = (const float*)d_in[8];
    const float* Wgu2 = (const float*)d_in[9]; const float* bgu2 = (const float*)d_in[10];
    const float* Wt0 = (const float*)d_in[11]; const float* bt0 = (const float*)d_in[12];
    const float* Wt1 = (const float*)d_in[13]; const float* bt1 = (const float*)d_in[14];
    const float* Wgt1 = (const float*)d_in[15]; const float* bgt1 = (const float*)d_in[16];
    const float* Wgt2 = (const float*)d_in[17]; const float* bgt2 = (const float*)d_in[18];
    const float* W_ih = (const float*)d_in[19]; const float* b_ih = (const float*)d_in[20];
    const float* W_hh = (const float*)d_in[21]; const float* b_hh = (const float*)d_in[22];
    const float* Wd0 = (const float*)d_in[23]; const float* bd0 = (const float*)d_in[24];
    const float* Wd1 = (const float*)d_in[25]; const float* bd1 = (const float*)d_in[26];
    const float* Wp  = (const float*)d_in[27]; const float* bp  = (const float*)d_in[28];
    const int* ue = (const int*)d_in[29];
    const int* te = (const int*)d_in[30];
    const int* ue_src = ue, *ue_dst = ue + EU;
    const int* te_src = te, *te_dst = te + NTE;

    // ---- workspace layout ----
    float* ws = (float*)d_ws;
    size_t o = 0;
    float* dinv_u = ws + o;     o += NU;
    float* dinv_t = ws + o;     o += NTNODES;       // contiguous after dinv_u
    float* user_pool = ws + o;  o += (size_t)BB * 128;
    float* tweet_h = ws + o;    o += (size_t)BB * 128;
    float* whhT = ws + o;       o += 128 * 384;
    float* gi = ws + o;         o += (size_t)NSEG_T * 384;
    float* pmax = ws + o;       o += 131072;
    float* pse = ws + o;        o += 131072;
    float* pacc = ws + o;       o += 131072;
    int* iw = (int*)(ws + o);
    int* hist_u = iw;
    int* hist_t = iw + NU;
    int* ptr_u  = iw + NU + NTNODES;
    int* fill_u = ptr_u + NU + 1;
    int* esrc_u = fill_u + NU;
    int* ptr_t  = esrc_u + EU;
    int* fill_t = ptr_t + NTNODES + 1;
    int* esrc_t = fill_t + NTNODES;
    int* bsum_u = esrc_t + NTE;
    int* bsum_t = bsum_u + 256;
    unsigned short* pk = (unsigned short*)(((uintptr_t)(bsum_t + 256) + 15) & ~(uintptr_t)15);
    unsigned short* pWu0  = pk;
    unsigned short* pWu1  = pWu0  + 16384;
    unsigned short* pWgu1 = pWu1  + 16384;
    unsigned short* pWgu2 = pWgu1 + 16384;
    unsigned short* pWt0  = pWgu2 + 16384;
    unsigned short* pWt1  = pWt0  + 196608;
    unsigned short* pWgt1 = pWt1  + 32768;
    unsigned short* pWgt2 = pWgt1 + 16384;
    unsigned short* pWih  = pWgt2 + 16384;
    // bf16 arena: 4 slots of NT*256 halfwords
    unsigned short* arena = (unsigned short*)(((uintptr_t)(pWih + 49152) + 15) & ~(uintptr_t)15);
    const size_t SLOT = (size_t)NTNODES * 256;      // 7,864,320 hw
    unsigned short* P0 = arena;
    unsigned short* P1 = P0 + SLOT;
    unsigned short* P2 = P1 + SLOT;
    unsigned short* P3 = P2 + SLOT;
    unsigned short* tpool_bf = P3 + SLOT;           // 1024*128 hw
    float* out = (float*)d_out;

    dim3 b256(256);
    const float* ND = nullptr;

    // ---- packs + whh transpose ----
    hipLaunchKernelGGL(k_packall, dim3((425984 + 255) / 256), b256, 0, stream,
                       Wu0, Wu1, Wgu1, Wgu2, Wt0, Wt1, Wgt1, Wgt2, W_ih, W_hh, whhT, pk);

    // ---- degrees + CSR (fused user+tweet) ----
    hipLaunchKernelGGL(k_zeroint, dim3((NU + NTNODES + 255) / 256), b256, 0, stream,
                       hist_u, NU + NTNODES);
    hipLaunchKernelGGL(k_hist2, dim3((EU + NTE + 255) / 256), b256, 0, stream,
                       ue_dst, te_dst, hist_u, hist_t);
    hipLaunchKernelGGL(k_scan_a2, dim3(NBU + NBT), b256, 0, stream, hist_u, bsum_u, bsum_t);
    hipLaunchKernelGGL(k_scan_b2, dim3(2), b256, 0, stream, bsum_u, bsum_t);
    hipLaunchKernelGGL(k_scan_c2, dim3(NBU + NBT), b256, 0, stream,
                       hist_u, bsum_u, bsum_t, ptr_u, fill_u, ptr_t, fill_t, dinv_u);
    hipLaunchKernelGGL(k_place2, dim3((EU + NTE + 255) / 256), b256, 0, stream,
                       ue_src, ue_dst, te_src, te_dst, fill_u, esrc_u, fill_t, esrc_t);

    // ---- J1: tweet conv1 (fp32 A, NPAN=2 -> P0 [NT,256]) + user gemm1 (NPAN=1 -> P2) ----
    hipLaunchKernelGGL(HIP_KERNEL_NAME(k_mgemm_dual<true, 2, 1>), dim3(NU / 32, 2), b256, 0, stream,
                       (const void*)tweet_x, pWt0, dinv_t, (void*)P0, NTNODES, 768, 256,
                       (const void*)user_x,  pWu0, dinv_u, (void*)P2, NU,      128, 128,
                       1);
    // ---- J2: tweet gagg1 (P0 -> h1t@P1) + user gagg1 (P2 -> h1u@P3) ----
    hipLaunchKernelGGL(k_gagg2, dim3((NTNODES * 2 + NU + 3) / 4), b256, 0, stream,
                       P0, ptr_t, esrc_t, dinv_t, bt0, P1, NTNODES, 2,
                       P2, ptr_u, esrc_u, dinv_u, bu0, P3, NU, 1);
    // ---- J3: tweet gemm2 (h1t@P1 -> y2t'@P2) + user gemm2 (h1u@P3 -> y2u'@P0) ----
    hipLaunchKernelGGL(HIP_KERNEL_NAME(k_mgemm_dual<false, 1, 1>), dim3(NU / 32, 2), b256, 0, stream,
                       (const void*)P1, pWt1, dinv_t, (void*)P2, NTNODES, 256, 128,
                       (const void*)P3, pWu1, dinv_u, (void*)P0, NU,      128, 128,
                       1);
    // ---- J4: tweet gagg2 (P2 -> g2t@P1) + user gagg2 (P0 -> h2u@P3) ----
    hipLaunchKernelGGL(k_gagg2, dim3((NTNODES + NU + 3) / 4), b256, 0, stream,
                       P2, ptr_t, esrc_t, dinv_t, bt1, P1, NTNODES, 1,
                       P0, ptr_u, esrc_u, dinv_u, bu1, P3, NU, 1);
    // ---- J5: user gatepair (h2u@P3 -> gate_u@P0) + tweet gatepair (g2t@P1 -> gate_t@P2) ----
    hipLaunchKernelGGL(k_gatepair2, dim3(NU / 64 + NTNODES / 64), b256, 0, stream,
                       P3, pWgu1, bgu1, pWgu2, bgu2, P0, NU / 64,
                       P1, pWgt1, bgt1, pWgt2, bgt2, P2);

    // ---- pools ----
    hipLaunchKernelGGL(k_pool_pmax, dim3(BB, NCHUNK), b256, 0, stream, P0, pmax, NU / BB);
    hipLaunchKernelGGL(k_pool_psum, dim3(BB, NCHUNK), b256, 0, stream,
                       P3, P0, pmax, pse, pacc, NU / BB);
    hipLaunchKernelGGL(k_pool_final, dim3(BB), dim3(128), 0, stream, pse, pacc, user_pool);
    hipLaunchKernelGGL(k_attpool, dim3(NSEG_T), dim3(128), 0, stream,
                       P1, P2, tpool_bf, NW);

    // ---- GRU: gi = tweet_pool @ W_ih^T + b_ih (fp32 out) ----
    hipLaunchKernelGGL(HIP_KERNEL_NAME(k_mgemm<false>), dim3(NSEG_T / 32, 3), b256, 0, stream,
                       (const void*)tpool_bf, pWih, b_ih, ND, (void*)gi, NSEG_T, 128, 384, 5);
    hipLaunchKernelGGL(k_gru_rec, dim3(BB), dim3(768), 0, stream,
                       gi, whhT, b_hh, tweet_h);

    // ---- head ----
    hipLaunchKernelGGL(k_head, dim3(BB), b256, 0, stream,
                       user_feats, user_pool, tweet_h,
                       Wd0, bd0, Wd1, bd1, Wp, bp, out);
}